// Round 2
// baseline (1037.048 us; speedup 1.0000x reference)
//
#include <hip/hip_runtime.h>

#define NUSERS 50000
#define NITEMS 20000
#define NEDGES 400000

typedef _Float16 f16;
typedef __attribute__((ext_vector_type(8))) _Float16 f16x8;
typedef __attribute__((ext_vector_type(4))) _Float16 f16x4;
typedef __attribute__((ext_vector_type(2))) _Float16 f16x2;
typedef __attribute__((ext_vector_type(4))) float f32x4;

// ---------- prep: weight transpose->f16 + folded el/er projections, both relations ----------
__global__ void prep_k(const float* __restrict__ Wa, const float* __restrict__ Aa,
                       f16* __restrict__ Bta, float* __restrict__ efa,
                       const float* __restrict__ Wb, const float* __restrict__ Ab,
                       f16* __restrict__ Btb, float* __restrict__ efb,
                       int K, int Nw, int dh) {
  int t = blockIdx.x * blockDim.x + threadIdx.x;
  int half = K * Nw;
  if (t >= 2 * half) return;
  const float* W = (t < half) ? Wa : Wb;
  const float* A = (t < half) ? Aa : Ab;
  f16* Bt = (t < half) ? Bta : Btb;
  float* ef = (t < half) ? efa : efb;
  int t2 = (t < half) ? t : t - half;
  int n = t2 / K, k = t2 - n * K;
  Bt[t2] = (f16)W[(long)k * Nw + n];
  if (t2 < K * 8) {
    int j = t2 / (K * 4);
    int r = t2 - j * K * 4;
    int h = r / K, f = r - h * K;
    const float* Aj = A + j * Nw;   // A[j], shape [4,dh], Nw = 4*dh
    float s = 0.f;
    for (int d = 0; d < dh; ++d) s += W[f * Nw + h * dh + d] * Aj[h * dh + d];
    ef[j * 4 * K + h * K + f] = s;
  }
}

// ---------- fp32 -> f16 convert, both sides in one launch ----------
__global__ void xcvt_k(const float* __restrict__ xu, f16* __restrict__ yu, long nu,
                       const float* __restrict__ xi, f16* __restrict__ yi, long ni) {
  long i = (long)blockIdx.x * blockDim.x + threadIdx.x;
  if (i < nu) yu[i] = (f16)xu[i];
  else if (i < nu + ni) yi[i - nu] = (f16)xi[i - nu];
}

// ---------- f16 MFMA GEMM, user+item fused: C = A[M,K] @ Bt[N,K]^T ----------
__global__ __launch_bounds__(256) void hgemm2_k(const f16* __restrict__ Aa, const f16* __restrict__ Bta,
                                                f16* __restrict__ Ca, int Ma, int gya,
                                                const f16* __restrict__ Ab, const f16* __restrict__ Btb,
                                                f16* __restrict__ Cb, int Mb,
                                                int N, int K) {
  __shared__ f16 As[128 * 32];
  __shared__ f16 Bs[128 * 32];
  int by = blockIdx.y;
  const f16* A; const f16* Bt; f16* C; int M; int row0;
  if (by < gya) { A = Aa; Bt = Bta; C = Ca; M = Ma; row0 = by * 128; }
  else          { A = Ab; Bt = Btb; C = Cb; M = Mb; row0 = (by - gya) * 128; }
  int tid = threadIdx.x;
  int col0 = blockIdx.x * 128;
  int lane = tid & 63, wv = tid >> 6;
  int wr = (wv & 1) * 64, wc = (wv >> 1) * 64;
  int l16 = lane & 15, q = lane >> 4;
  f32x4 acc[4][4] = {};
  int r = tid >> 2, c8 = (tid & 3) * 8;
  for (int k0 = 0; k0 < K; k0 += 32) {
    int ra = min(row0 + r, M - 1);
    uint4 va = *(const uint4*)&A[(long)ra * K + k0 + c8];
    int ra2 = min(row0 + r + 64, M - 1);
    uint4 va2 = *(const uint4*)&A[(long)ra2 * K + k0 + c8];
    uint4 vb = *(const uint4*)&Bt[(long)(col0 + r) * K + k0 + c8];
    uint4 vb2 = *(const uint4*)&Bt[(long)(col0 + r + 64) * K + k0 + c8];
    *(uint4*)&As[r * 32 + c8] = va;
    *(uint4*)&As[(r + 64) * 32 + c8] = va2;
    *(uint4*)&Bs[r * 32 + c8] = vb;
    *(uint4*)&Bs[(r + 64) * 32 + c8] = vb2;
    __syncthreads();
    f16x8 af[4], bfr[4];
#pragma unroll
    for (int i = 0; i < 4; ++i) {
      af[i] = *(const f16x8*)&As[(wr + i * 16 + l16) * 32 + q * 8];
      bfr[i] = *(const f16x8*)&Bs[(wc + i * 16 + l16) * 32 + q * 8];
    }
#pragma unroll
    for (int i = 0; i < 4; ++i)
#pragma unroll
      for (int j = 0; j < 4; ++j)
        acc[i][j] = __builtin_amdgcn_mfma_f32_16x16x32_f16(af[i], bfr[j], acc[i][j], 0, 0, 0);
    __syncthreads();
  }
#pragma unroll
  for (int i = 0; i < 4; ++i) {
#pragma unroll
    for (int reg = 0; reg < 4; ++reg) {
      int rr = row0 + wr + i * 16 + q * 4 + reg;
      if (rr < M) {
#pragma unroll
        for (int j = 0; j < 4; ++j)
          C[(long)rr * N + col0 + wc + j * 16 + l16] = (f16)acc[i][j][reg];
      }
    }
  }
}

// ---------- el+er via folds (layer 0 only); block per node ----------
__global__ __launch_bounds__(256) void eler_k(
    const f16* __restrict__ hbu, const float* __restrict__ ef_ui, const float* __restrict__ ef_iu,
    float* __restrict__ el_u, float* __restrict__ er_u,
    const f16* __restrict__ hbi, float* __restrict__ el_i, float* __restrict__ er_i, int K) {
  __shared__ float xs[256];
  int b = blockIdx.x, t = threadIdx.x;
  const f16* hb; const float* elf; const float* erf; float* el; float* er; int n;
  if (b < NUSERS) { hb = hbu; elf = ef_ui; erf = ef_iu + 4 * K; el = el_u; er = er_u; n = b; }
  else            { hb = hbi; elf = ef_iu; erf = ef_ui + 4 * K; el = el_i; er = er_i; n = b - NUSERS; }
  if (t < K) xs[t] = (float)hb[(long)n * K + t];
  __syncthreads();
  int j = t >> 5, l = t & 31;
  const float* fr = (j < 4) ? (elf + j * K) : (erf + (j - 4) * K);
  float p = 0.f;
  for (int f = l; f < K; f += 32) p += xs[f] * fr[f];
#pragma unroll
  for (int off = 16; off; off >>= 1) p += __shfl_down(p, off, 32);
  if (l == 0) { if (j < 4) el[n * 4 + j] = p; else er[n * 4 + (j - 4)] = p; }
}

// ---------- CSR build ----------
__global__ void hist_k(const int* __restrict__ ei, int* __restrict__ degi,
                       const int* __restrict__ eu, int* __restrict__ degu) {
  int e = blockIdx.x * blockDim.x + threadIdx.x;
  if (e < NEDGES) atomicAdd(&degi[ei[e]], 1);
  else if (e < 2 * NEDGES) atomicAdd(&degu[eu[e - NEDGES]], 1);
}

__global__ __launch_bounds__(256) void scan1_k(const int* __restrict__ deg,
                                               int* __restrict__ bsum, int N) {
  __shared__ int red[256];
  int base = blockIdx.x * 1024, t = threadIdx.x;
  int s = 0;
#pragma unroll
  for (int j = 0; j < 4; ++j) { int i = base + t * 4 + j; s += (i < N) ? deg[i] : 0; }
  red[t] = s; __syncthreads();
  for (int off = 128; off; off >>= 1) { if (t < off) red[t] += red[t + off]; __syncthreads(); }
  if (t == 0) bsum[blockIdx.x] = red[0];
}

__global__ void scan2_k(int* __restrict__ bsum, int nb) {
  if (threadIdx.x == 0) {
    int run = 0;
    for (int i = 0; i < nb; ++i) { int v = bsum[i]; bsum[i] = run; run += v; }
  }
}

__global__ __launch_bounds__(256) void scan3_k(const int* __restrict__ deg,
                                               const int* __restrict__ bsum,
                                               int* __restrict__ rowptr, int N) {
  __shared__ int tsum[256];
  int base = blockIdx.x * 1024, t = threadIdx.x;
  int v[4]; int s = 0;
#pragma unroll
  for (int j = 0; j < 4; ++j) { int i = base + t * 4 + j; v[j] = (i < N) ? deg[i] : 0; s += v[j]; }
  tsum[t] = s; __syncthreads();
  for (int off = 1; off < 256; off <<= 1) {
    int x = (t >= off) ? tsum[t - off] : 0;
    __syncthreads();
    tsum[t] += x;
    __syncthreads();
  }
  int run = bsum[blockIdx.x] + ((t > 0) ? tsum[t - 1] : 0);
#pragma unroll
  for (int j = 0; j < 4; ++j) {
    int i = base + t * 4 + j;
    if (i < N) rowptr[i] = run;
    run += v[j];
  }
}

__global__ void setval_k(int* __restrict__ p, int v) { *p = v; }

__global__ void copy2_k(const int* __restrict__ a, int* __restrict__ b, int Na,
                        const int* __restrict__ c, int* __restrict__ d, int Nc) {
  int i = blockIdx.x * blockDim.x + threadIdx.x;
  if (i < Na) b[i] = a[i];
  else if (i < Na + Nc) d[i - Na] = c[i - Na];
}

__global__ void scat_k(const int* __restrict__ ei, const int* __restrict__ eu,
                       int* __restrict__ curi, int* __restrict__ srci,
                       int* __restrict__ curu, int* __restrict__ srcu) {
  int e = blockIdx.x * blockDim.x + threadIdx.x;
  if (e < NEDGES) {
    int p = atomicAdd(&curi[ei[e]], 1);
    srci[p] = eu[e];
  } else if (e < 2 * NEDGES) {
    int e2 = e - NEDGES;
    int p = atomicAdd(&curu[eu[e2]], 1);
    srcu[p] = ei[e2];
  }
}

// ---------- softmax numerators: p = exp(leaky(el[src]+er[dst])) per CSR slot ----------
// No max subtraction: logits are dots of ~unit-variance features with 0.1-scale
// weights (|logit| <~ 10), exp() is far from f32 overflow; alpha identical.
// Stores p to 4 head-planes [h*P + slot] so the gather reads contiguous float4,
// and reduces S[d*4+h] = sum(p) per dst via one butterfly (no atomics).
__global__ __launch_bounds__(256) void sfm_k(
    const float* __restrict__ elA, const float* __restrict__ erA,
    const int* __restrict__ rpA, const int* __restrict__ srcA,
    float* __restrict__ pxA, float* __restrict__ SA, int nA,
    const float* __restrict__ elB, const float* __restrict__ erB,
    const int* __restrict__ rpB, const int* __restrict__ srcB,
    float* __restrict__ pxB, float* __restrict__ SB, int nB, int P) {
  int wv = threadIdx.x >> 6;
  int g = blockIdx.x * 4 + wv;
  int lane = threadIdx.x & 63;
  const float* el; const float* er; const int* rp; const int* srcv;
  float* px; float* S; int d;
  if (g < nA)           { el = elA; er = erA; rp = rpA; srcv = srcA; px = pxA; S = SA; d = g; }
  else if (g < nA + nB) { el = elB; er = erB; rp = rpB; srcv = srcB; px = pxB; S = SB; d = g - nA; }
  else return;
  int s0 = rp[d], s1 = rp[d + 1];
  float4 er4 = *(const float4*)&er[d * 4];
  float a0 = 0.f, a1 = 0.f, a2 = 0.f, a3 = 0.f;
  for (int k = s0 + lane; k < s1; k += 64) {
    int s = srcv[k];
    float4 e4 = *(const float4*)&el[(size_t)s * 4];
    float v0 = e4.x + er4.x; v0 = v0 > 0.f ? v0 : 0.2f * v0; float p0 = __expf(v0);
    float v1 = e4.y + er4.y; v1 = v1 > 0.f ? v1 : 0.2f * v1; float p1 = __expf(v1);
    float v2 = e4.z + er4.z; v2 = v2 > 0.f ? v2 : 0.2f * v2; float p2 = __expf(v2);
    float v3 = e4.w + er4.w; v3 = v3 > 0.f ? v3 : 0.2f * v3; float p3 = __expf(v3);
    px[k] = p0; px[P + k] = p1; px[2 * P + k] = p2; px[3 * P + k] = p3;
    a0 += p0; a1 += p1; a2 += p2; a3 += p3;
  }
#pragma unroll
  for (int off = 32; off; off >>= 1) {
    a0 += __shfl_xor(a0, off, 64);
    a1 += __shfl_xor(a1, off, 64);
    a2 += __shfl_xor(a2, off, 64);
    a3 += __shfl_xor(a3, off, 64);
  }
  if (lane == 0) *(float4*)&S[d * 4] = make_float4(a0, a1, a2, a3);
}

// ---------- pure gather: out[d] = (sum_e p_e * hs[src_e]) / S[d]; wave per dst ----------
// No softmax, no LDS, no shuffles: per chunk of 4 slots (16B-aligned so int4/
// float4 loads are legal), issue 4 row loads then FMA. Only first/last chunk
// masks the out-of-segment lanes (p=0, src clamped to row 0).
template <int W, int DH, typename OUT>
__global__ __launch_bounds__(256) void agg_k(
    const int* __restrict__ rpA, const int* __restrict__ srcA,
    const float* __restrict__ pxA, const float* __restrict__ SA,
    const f16* __restrict__ hsA, OUT* __restrict__ outA, int nA,
    const int* __restrict__ rpB, const int* __restrict__ srcB,
    const float* __restrict__ pxB, const float* __restrict__ SB,
    const f16* __restrict__ hsB, OUT* __restrict__ outB, int nB, int P) {
  constexpr int CPL = W >> 6;                   // channels per lane
  constexpr int SHIFT = (W == 256) ? 9 : 8;     // log2(W * sizeof(f16))
  constexpr bool OF16 = (sizeof(OUT) == 2);
  int wv = threadIdx.x >> 6;
  int g = blockIdx.x * 4 + wv;
  int lane = threadIdx.x & 63;
  const int* rp; const int* srcv; const float* px; const float* Sv;
  const f16* hs; OUT* outp; int d;
  if (g < nA)           { rp = rpA; srcv = srcA; px = pxA; Sv = SA; hs = hsA; outp = outA; d = g; }
  else if (g < nA + nB) { rp = rpB; srcv = srcB; px = pxB; Sv = SB; hs = hsB; outp = outB; d = g - nA; }
  else return;
  int s0 = rp[d], s1 = rp[d + 1];
  int deg = s1 - s0;
  int c0 = lane * CPL;
  int h = lane >> 4;                            // c0/DH for both W=256,DH=64 and W=128,DH=32
  long obase = (long)d * W + c0;
  if (deg == 0) {
#pragma unroll
    for (int q = 0; q < CPL; ++q) outp[obase + q] = (OUT)0.f;
    return;
  }
  float inv = 1.0f / Sv[d * 4 + h];
  const float* pl = px + (size_t)h * P;
  const char* hbase = (const char*)hs + (size_t)c0 * sizeof(f16);
  float acc[CPL];
#pragma unroll
  for (int q = 0; q < CPL; ++q) acc[q] = 0.f;
  int a0 = s0 & ~3;
  int nch = (s1 - a0 + 3) >> 2;
  for (int ch = 0; ch < nch; ++ch) {
    int k = a0 + ch * 4;
    int4 s4 = *(const int4*)&srcv[k];
    float4 p4 = *(const float4*)&pl[k];
    if (ch == 0 || ch == nch - 1) {
      bool v0 = (k     >= s0) & (k     < s1);
      bool v1 = (k + 1 >= s0) & (k + 1 < s1);
      bool v2 = (k + 2 >= s0) & (k + 2 < s1);
      bool v3 = (k + 3 >= s0) & (k + 3 < s1);
      p4.x = v0 ? p4.x : 0.f; s4.x = v0 ? s4.x : 0;
      p4.y = v1 ? p4.y : 0.f; s4.y = v1 ? s4.y : 0;
      p4.z = v2 ? p4.z : 0.f; s4.z = v2 ? s4.z : 0;
      p4.w = v3 ? p4.w : 0.f; s4.w = v3 ? s4.w : 0;
    }
    if constexpr (CPL == 4) {
      f16x4 r0 = *(const f16x4*)(hbase + ((size_t)(unsigned)s4.x << SHIFT));
      f16x4 r1 = *(const f16x4*)(hbase + ((size_t)(unsigned)s4.y << SHIFT));
      f16x4 r2 = *(const f16x4*)(hbase + ((size_t)(unsigned)s4.z << SHIFT));
      f16x4 r3 = *(const f16x4*)(hbase + ((size_t)(unsigned)s4.w << SHIFT));
      acc[0] += p4.x * (float)r0[0]; acc[1] += p4.x * (float)r0[1];
      acc[2] += p4.x * (float)r0[2]; acc[3] += p4.x * (float)r0[3];
      acc[0] += p4.y * (float)r1[0]; acc[1] += p4.y * (float)r1[1];
      acc[2] += p4.y * (float)r1[2]; acc[3] += p4.y * (float)r1[3];
      acc[0] += p4.z * (float)r2[0]; acc[1] += p4.z * (float)r2[1];
      acc[2] += p4.z * (float)r2[2]; acc[3] += p4.z * (float)r2[3];
      acc[0] += p4.w * (float)r3[0]; acc[1] += p4.w * (float)r3[1];
      acc[2] += p4.w * (float)r3[2]; acc[3] += p4.w * (float)r3[3];
    } else {
      f16x2 r0 = *(const f16x2*)(hbase + ((size_t)(unsigned)s4.x << SHIFT));
      f16x2 r1 = *(const f16x2*)(hbase + ((size_t)(unsigned)s4.y << SHIFT));
      f16x2 r2 = *(const f16x2*)(hbase + ((size_t)(unsigned)s4.z << SHIFT));
      f16x2 r3 = *(const f16x2*)(hbase + ((size_t)(unsigned)s4.w << SHIFT));
      acc[0] += p4.x * (float)r0[0]; acc[1] += p4.x * (float)r0[1];
      acc[0] += p4.y * (float)r1[0]; acc[1] += p4.y * (float)r1[1];
      acc[0] += p4.z * (float)r2[0]; acc[1] += p4.z * (float)r2[1];
      acc[0] += p4.w * (float)r3[0]; acc[1] += p4.w * (float)r3[1];
    }
  }
  if constexpr (OF16) {
    if constexpr (CPL == 4) {
      f16x4 o = { (f16)(acc[0] * inv), (f16)(acc[1] * inv), (f16)(acc[2] * inv), (f16)(acc[3] * inv) };
      *(f16x4*)&outp[obase] = o;
    } else {
      f16x2 o = { (f16)(acc[0] * inv), (f16)(acc[1] * inv) };
      *(f16x2*)&outp[obase] = o;
    }
  } else {
    if constexpr (CPL == 4) {
      *(float4*)&outp[obase] = make_float4(acc[0] * inv, acc[1] * inv, acc[2] * inv, acc[3] * inv);
    } else {
      *(float2*)&outp[obase] = make_float2(acc[0] * inv, acc[1] * inv);
    }
  }
}

// ---------- BN zero ----------
__global__ void zero2_k(float* __restrict__ a, float* __restrict__ b) {
  int t = threadIdx.x;
  a[t] = 0.f; b[t] = 0.f;
}

// ---------- BN stats (f16 input), both sides ----------
__global__ __launch_bounds__(256) void bn_stats2_k(const f16* __restrict__ xu, float* __restrict__ su, int Nu, int gU,
                                                   const f16* __restrict__ xi, float* __restrict__ si, int Ni) {
  const int C = 256;
  int b = blockIdx.x;
  const f16* x; float* sums; int N; int r0;
  if (b < gU) { x = xu; sums = su; N = Nu; r0 = b * 64; }
  else        { x = xi; sums = si; N = Ni; r0 = (b - gU) * 64; }
  int c = threadIdx.x;
  int r1 = min(r0 + 64, N);
  float s = 0.f, s2 = 0.f;
  for (int r = r0; r < r1; ++r) {
    float v = (float)x[(long)r * C + c];
    s += v; s2 += v * v;
  }
  atomicAdd(&sums[c], s);
  atomicAdd(&sums[C + c], s2);
}

// ---------- fused BN apply + activation -> f16 AND next-layer el/er; block per row ----------
__global__ __launch_bounds__(256) void bn_fused_k(
    const f16* __restrict__ xu, const float* __restrict__ su, const float* __restrict__ gbu,
    f16* __restrict__ yu, int Nu,
    const f16* __restrict__ xi, const float* __restrict__ si, const float* __restrict__ gbi,
    f16* __restrict__ yi, int Ni,
    const float* __restrict__ efu, const float* __restrict__ efiu,   // next-layer folds, K=256
    float* __restrict__ el_u, float* __restrict__ er_u,
    float* __restrict__ el_i, float* __restrict__ er_i, int act) {
  const int Kn = 256;
  __shared__ float xs[256];
  int b = blockIdx.x, t = threadIdx.x;
  const f16* x; const float* sums; const float* gb; f16* y; int n; int N;
  const float* elf; const float* erf; float* el; float* er;
  if (b < Nu) { x = xu; sums = su; gb = gbu; y = yu; n = b; N = Nu; elf = efu;  erf = efiu + 4 * Kn; el = el_u; er = er_u; }
  else        { x = xi; sums = si; gb = gbi; y = yi; n = b - Nu; N = Ni; elf = efiu; erf = efu + 4 * Kn;  el = el_i; er = er_i; }
  long base = (long)n * 256;
  float val = (float)x[base + t];
  float inv_n = 1.0f / (float)N;
  float mean = sums[t] * inv_n;
  float var = sums[256 + t] * inv_n - mean * mean;
  float v = gb[t] * (val - mean) * rsqrtf(var + 1e-5f) + gb[256 + t];
  v = act ? tanhf(v) : (v > 0.f ? v : 0.01f * v);
  y[base + t] = (f16)v;
  xs[t] = v;
  __syncthreads();
  int j = t >> 5, l = t & 31;
  const float* fr = (j < 4) ? (elf + j * Kn) : (erf + (j - 4) * Kn);
  float p = 0.f;
  for (int f = l; f < Kn; f += 32) p += xs[f] * fr[f];
#pragma unroll
  for (int off = 16; off; off >>= 1) p += __shfl_down(p, off, 32);
  if (l == 0) { if (j < 4) el[n * 4 + j] = p; else er[n * 4 + (j - 4)] = p; }
}

extern "C" void kernel_launch(void* const* d_in, const int* in_sizes, int n_in,
                              void* d_out, int out_size, void* d_ws, size_t ws_size,
                              hipStream_t stream) {
  const float* x_user = (const float*)d_in[0];
  const float* x_item = (const float*)d_in[1];
  const int* eu = (const int*)d_in[2];
  const int* ei = (const int*)d_in[3];
  const float *Wm[4][2], *Am[4][2];
  for (int L = 0; L < 4; ++L) {
    Wm[L][0] = (const float*)d_in[4 + L * 4 + 0];
    Am[L][0] = (const float*)d_in[4 + L * 4 + 1];
    Wm[L][1] = (const float*)d_in[4 + L * 4 + 2];
    Am[L][1] = (const float*)d_in[4 + L * 4 + 3];
  }
  const float* bnu = (const float*)d_in[20];
  const float* bni = (const float*)d_in[21];
  float* out = (float*)d_out;

  const int PP = NEDGES + 4;   // head-plane stride for pexp (padded, 16B-aligned)

  float* ws = (float*)d_ws;
  size_t o = 0;
  float* el_u = ws + o; o += (size_t)NUSERS * 4;
  float* er_u = ws + o; o += (size_t)NUSERS * 4;
  float* el_i = ws + o; o += (size_t)NITEMS * 4;
  float* er_i = ws + o; o += (size_t)NITEMS * 4;
  float* ef_all[4][2];
  for (int L = 0; L < 4; ++L)
    for (int rl = 0; rl < 2; ++rl) { ef_all[L][rl] = ws + o; o += 2048; }
  float* bns_u = ws + o; o += 512;
  float* bns_i = ws + o; o += 512;
  float* S_u = ws + o; o += (size_t)NUSERS * 4;
  float* S_i = ws + o; o += (size_t)NITEMS * 4;
  float* pexp_i = ws + o; o += (size_t)4 * PP + 4;   // 4 head planes + over-read pad
  float* pexp_u = ws + o; o += (size_t)4 * PP + 4;
  // f16 buffers (offsets in float units; all 16B aligned)
  f16* hb_u   = (f16*)(ws + o); o += (size_t)NUSERS * 128;
  f16* hb_i   = (f16*)(ws + o); o += (size_t)NITEMS * 128;
  f16* hsb_u  = (f16*)(ws + o); o += (size_t)NUSERS * 128;
  f16* hsb_i  = (f16*)(ws + o); o += (size_t)NITEMS * 128;
  f16* aggh_u = (f16*)(ws + o); o += (size_t)NUSERS * 128;
  f16* aggh_i = (f16*)(ws + o); o += (size_t)NITEMS * 128;
  f16* Bt_all[4][2];
  for (int L = 0; L < 4; ++L) {
    int K = (L == 0) ? 128 : 256;
    int W = (L == 3) ? 128 : 256;
    for (int rl = 0; rl < 2; ++rl) { Bt_all[L][rl] = (f16*)(ws + o); o += (size_t)K * W / 2; }
  }
  // CSR scratch (deg_i/deg_u adjacent => single memset); sizes padded to keep 16B alignment
  int* deg_i    = (int*)(ws + o); o += NITEMS;
  int* deg_u    = (int*)(ws + o); o += NUSERS;
  int* rowptr_i = (int*)(ws + o); o += NITEMS + 4;
  int* rowptr_u = (int*)(ws + o); o += NUSERS + 4;
  int* cur_i    = (int*)(ws + o); o += NITEMS;
  int* cur_u    = (int*)(ws + o); o += NUSERS;
  int* bsum     = (int*)(ws + o); o += 256;
  int* csrsrc_i = (int*)(ws + o); o += NEDGES + 4;   // +4: aligned int4 over-read pad
  int* csrsrc_u = (int*)(ws + o); o += NEDGES + 4;

  const int gE2 = (2 * NEDGES + 255) / 256;
  const int nb_i = (NITEMS + 1023) / 1024;
  const int nb_u = (NUSERS + 1023) / 1024;
  const int gU = (NUSERS + 63) / 64;
  const int gI = (NITEMS + 63) / 64;

  // ---- CSR build (once; edges identical across layers) ----
  hipMemsetAsync(deg_i, 0, (NITEMS + NUSERS) * sizeof(int), stream);
  hist_k<<<dim3(gE2), dim3(256), 0, stream>>>(ei, deg_i, eu, deg_u);
  scan1_k<<<dim3(nb_i), dim3(256), 0, stream>>>(deg_i, bsum, NITEMS);
  scan2_k<<<dim3(1), dim3(64), 0, stream>>>(bsum, nb_i);
  scan3_k<<<dim3(nb_i), dim3(256), 0, stream>>>(deg_i, bsum, rowptr_i, NITEMS);
  setval_k<<<dim3(1), dim3(1), 0, stream>>>(rowptr_i + NITEMS, NEDGES);
  scan1_k<<<dim3(nb_u), dim3(256), 0, stream>>>(deg_u, bsum, NUSERS);
  scan2_k<<<dim3(1), dim3(64), 0, stream>>>(bsum, nb_u);
  scan3_k<<<dim3(nb_u), dim3(256), 0, stream>>>(deg_u, bsum, rowptr_u, NUSERS);
  setval_k<<<dim3(1), dim3(1), 0, stream>>>(rowptr_u + NUSERS, NEDGES);
  copy2_k<<<dim3((NITEMS + NUSERS + 255) / 256), dim3(256), 0, stream>>>(rowptr_i, cur_i, NITEMS, rowptr_u, cur_u, NUSERS);
  scat_k<<<dim3(gE2), dim3(256), 0, stream>>>(ei, eu, cur_i, csrsrc_i, cur_u, csrsrc_u);

  // ---- all layer preps upfront (Bt + el/er folds) ----
  for (int L = 0; L < 4; ++L) {
    int K = (L == 0) ? 128 : 256;
    int dh = (L == 3) ? 32 : 64;
    int W = 4 * dh;
    prep_k<<<dim3((2 * K * W + 255) / 256), dim3(256), 0, stream>>>(
        Wm[L][0], Am[L][0], Bt_all[L][0], ef_all[L][0],
        Wm[L][1], Am[L][1], Bt_all[L][1], ef_all[L][1], K, W, dh);
  }

  // layer-0 inputs -> f16; layer-0 el/er
  xcvt_k<<<dim3(((NUSERS + NITEMS) * 128 + 255) / 256), dim3(256), 0, stream>>>(
      x_user, hb_u, (long)NUSERS * 128, x_item, hb_i, (long)NITEMS * 128);
  eler_k<<<dim3(NUSERS + NITEMS), dim3(256), 0, stream>>>(
      hb_u, ef_all[0][0], ef_all[0][1], el_u, er_u, hb_i, el_i, er_i, 128);

  int K = 128;
  const int gAgg = (NITEMS + NUSERS + 3) / 4;
  for (int L = 0; L < 4; ++L) {
    const int dh = (L == 3) ? 32 : 64;
    const int W = 4 * dh;

    const int gya = (NUSERS + 127) / 128, gyb = (NITEMS + 127) / 128;
    hgemm2_k<<<dim3(W / 128, gya + gyb), dim3(256), 0, stream>>>(
        hb_u, Bt_all[L][0], hsb_u, NUSERS, gya, hb_i, Bt_all[L][1], hsb_i, NITEMS, W, K);

    // softmax numerators + denominators for both relations
    sfm_k<<<dim3(gAgg), dim3(256), 0, stream>>>(
        el_u, er_i, rowptr_i, csrsrc_i, pexp_i, S_i, NITEMS,
        el_i, er_u, rowptr_u, csrsrc_u, pexp_u, S_u, NUSERS, PP);

    if (L < 3) {
      agg_k<256, 64, f16><<<dim3(gAgg), dim3(256), 0, stream>>>(
          rowptr_i, csrsrc_i, pexp_i, S_i, hsb_u, aggh_i, NITEMS,
          rowptr_u, csrsrc_u, pexp_u, S_u, hsb_i, aggh_u, NUSERS, PP);
      zero2_k<<<dim3(1), dim3(512), 0, stream>>>(bns_u, bns_i);
      bn_stats2_k<<<dim3(gU + gI), dim3(256), 0, stream>>>(aggh_u, bns_u, NUSERS, gU, aggh_i, bns_i, NITEMS);
      bn_fused_k<<<dim3(NUSERS + NITEMS), dim3(256), 0, stream>>>(
          aggh_u, bns_u, bnu + L * 512, hb_u, NUSERS,
          aggh_i, bns_i, bni + L * 512, hb_i, NITEMS,
          ef_all[L + 1][0], ef_all[L + 1][1],
          el_u, er_u, el_i, er_i, L == 2);
      K = 256;
    } else {
      agg_k<128, 32, float><<<dim3(gAgg), dim3(256), 0, stream>>>(
          rowptr_i, csrsrc_i, pexp_i, S_i, hsb_u, out + (size_t)NUSERS * 128, NITEMS,
          rowptr_u, csrsrc_u, pexp_u, S_u, hsb_i, out, NUSERS, PP);
    }
  }
}

// Round 3
// 971.159 us; speedup vs baseline: 1.0678x; 1.0678x over previous
//
#include <hip/hip_runtime.h>

#define NUSERS 50000
#define NITEMS 20000
#define NEDGES 400000

typedef _Float16 f16;
typedef __attribute__((ext_vector_type(8))) _Float16 f16x8;
typedef __attribute__((ext_vector_type(4))) _Float16 f16x4;
typedef __attribute__((ext_vector_type(2))) _Float16 f16x2;
typedef __attribute__((ext_vector_type(4))) float f32x4;
typedef __attribute__((ext_vector_type(2))) float f32x2;

// ---------- prep: weight transpose->f16 + folded el/er projections, both relations ----------
__global__ void prep_k(const float* __restrict__ Wa, const float* __restrict__ Aa,
                       f16* __restrict__ Bta, float* __restrict__ efa,
                       const float* __restrict__ Wb, const float* __restrict__ Ab,
                       f16* __restrict__ Btb, float* __restrict__ efb,
                       int K, int Nw, int dh) {
  int t = blockIdx.x * blockDim.x + threadIdx.x;
  int half = K * Nw;
  if (t >= 2 * half) return;
  const float* W = (t < half) ? Wa : Wb;
  const float* A = (t < half) ? Aa : Ab;
  f16* Bt = (t < half) ? Bta : Btb;
  float* ef = (t < half) ? efa : efb;
  int t2 = (t < half) ? t : t - half;
  int n = t2 / K, k = t2 - n * K;
  Bt[t2] = (f16)W[(long)k * Nw + n];
  if (t2 < K * 8) {
    int j = t2 / (K * 4);
    int r = t2 - j * K * 4;
    int h = r / K, f = r - h * K;
    const float* Aj = A + j * Nw;   // A[j], shape [4,dh], Nw = 4*dh
    float s = 0.f;
    for (int d = 0; d < dh; ++d) s += W[f * Nw + h * dh + d] * Aj[h * dh + d];
    ef[j * 4 * K + h * K + f] = s;
  }
}

// ---------- fp32 -> f16 convert, both sides in one launch ----------
__global__ void xcvt_k(const float* __restrict__ xu, f16* __restrict__ yu, long nu,
                       const float* __restrict__ xi, f16* __restrict__ yi, long ni) {
  long i = (long)blockIdx.x * blockDim.x + threadIdx.x;
  if (i < nu) yu[i] = (f16)xu[i];
  else if (i < nu + ni) yi[i - nu] = (f16)xi[i - nu];
}

// ---------- f16 MFMA GEMM, user+item fused: C = A[M,K] @ Bt[NTILE,K]^T ----------
// Single x-block covers all NTILE cols (A panel fetched ONCE). 4 waves:
// wave = 64 rows x (NTILE/2) cols. acc[4][JN] f32x4.
template <int NTILE>
__global__ __launch_bounds__(256) void hgemm_k(const f16* __restrict__ Aa, const f16* __restrict__ Bta,
                                               f16* __restrict__ Ca, int Ma, int gya,
                                               const f16* __restrict__ Ab, const f16* __restrict__ Btb,
                                               f16* __restrict__ Cb, int Mb, int K) {
  constexpr int JN = NTILE / 32;        // 8 for 256, 4 for 128
  constexpr int WC = NTILE / 2;         // wave col span
  constexpr int NB = NTILE / 64;        // B staging chunks
  __shared__ f16 As[128 * 32];
  __shared__ f16 Bs[NTILE * 32];
  int by = blockIdx.x;
  const f16* A; const f16* Bt; f16* C; int M; int row0;
  if (by < gya) { A = Aa; Bt = Bta; C = Ca; M = Ma; row0 = by * 128; }
  else          { A = Ab; Bt = Btb; C = Cb; M = Mb; row0 = (by - gya) * 128; }
  int tid = threadIdx.x;
  int lane = tid & 63, wv = tid >> 6;
  int wr = (wv & 1) * 64, wc = (wv >> 1) * WC;
  int l16 = lane & 15, q = lane >> 4;
  f32x4 acc[4][JN] = {};
  int r = tid >> 2, c8 = (tid & 3) * 8;
  for (int k0 = 0; k0 < K; k0 += 32) {
    int ra = min(row0 + r, M - 1);
    uint4 va = *(const uint4*)&A[(long)ra * K + k0 + c8];
    int ra2 = min(row0 + r + 64, M - 1);
    uint4 va2 = *(const uint4*)&A[(long)ra2 * K + k0 + c8];
    uint4 vb[NB];
#pragma unroll
    for (int c = 0; c < NB; ++c)
      vb[c] = *(const uint4*)&Bt[(long)(c * 64 + r) * K + k0 + c8];
    *(uint4*)&As[r * 32 + c8] = va;
    *(uint4*)&As[(r + 64) * 32 + c8] = va2;
#pragma unroll
    for (int c = 0; c < NB; ++c)
      *(uint4*)&Bs[(c * 64 + r) * 32 + c8] = vb[c];
    __syncthreads();
    f16x8 af[4], bfr[JN];
#pragma unroll
    for (int i = 0; i < 4; ++i)
      af[i] = *(const f16x8*)&As[(wr + i * 16 + l16) * 32 + q * 8];
#pragma unroll
    for (int j = 0; j < JN; ++j)
      bfr[j] = *(const f16x8*)&Bs[(wc + j * 16 + l16) * 32 + q * 8];
#pragma unroll
    for (int i = 0; i < 4; ++i)
#pragma unroll
      for (int j = 0; j < JN; ++j)
        acc[i][j] = __builtin_amdgcn_mfma_f32_16x16x32_f16(af[i], bfr[j], acc[i][j], 0, 0, 0);
    __syncthreads();
  }
#pragma unroll
  for (int i = 0; i < 4; ++i) {
#pragma unroll
    for (int reg = 0; reg < 4; ++reg) {
      int rr = row0 + wr + i * 16 + q * 4 + reg;
      if (rr < M) {
#pragma unroll
        for (int j = 0; j < JN; ++j)
          C[(long)rr * NTILE + wc + j * 16 + l16] = (f16)acc[i][j][reg];
      }
    }
  }
}

// ---------- el+er via folds (layer 0 only); block per node ----------
__global__ __launch_bounds__(256) void eler_k(
    const f16* __restrict__ hbu, const float* __restrict__ ef_ui, const float* __restrict__ ef_iu,
    float* __restrict__ el_u, float* __restrict__ er_u,
    const f16* __restrict__ hbi, float* __restrict__ el_i, float* __restrict__ er_i, int K) {
  __shared__ float xs[256];
  int b = blockIdx.x, t = threadIdx.x;
  const f16* hb; const float* elf; const float* erf; float* el; float* er; int n;
  if (b < NUSERS) { hb = hbu; elf = ef_ui; erf = ef_iu + 4 * K; el = el_u; er = er_u; n = b; }
  else            { hb = hbi; elf = ef_iu; erf = ef_ui + 4 * K; el = el_i; er = er_i; n = b - NUSERS; }
  if (t < K) xs[t] = (float)hb[(long)n * K + t];
  __syncthreads();
  int j = t >> 5, l = t & 31;
  const float* fr = (j < 4) ? (elf + j * K) : (erf + (j - 4) * K);
  float p = 0.f;
  for (int f = l; f < K; f += 32) p += xs[f] * fr[f];
#pragma unroll
  for (int off = 16; off; off >>= 1) p += __shfl_down(p, off, 32);
  if (l == 0) { if (j < 4) el[n * 4 + j] = p; else er[n * 4 + (j - 4)] = p; }
}

// ---------- CSR build ----------
__global__ void hist_k(const int* __restrict__ ei, int* __restrict__ degi,
                       const int* __restrict__ eu, int* __restrict__ degu) {
  int e = blockIdx.x * blockDim.x + threadIdx.x;
  if (e < NEDGES) atomicAdd(&degi[ei[e]], 1);
  else if (e < 2 * NEDGES) atomicAdd(&degu[eu[e - NEDGES]], 1);
}

__global__ __launch_bounds__(256) void scan1_k(const int* __restrict__ deg,
                                               int* __restrict__ bsum, int N) {
  __shared__ int red[256];
  int base = blockIdx.x * 1024, t = threadIdx.x;
  int s = 0;
#pragma unroll
  for (int j = 0; j < 4; ++j) { int i = base + t * 4 + j; s += (i < N) ? deg[i] : 0; }
  red[t] = s; __syncthreads();
  for (int off = 128; off; off >>= 1) { if (t < off) red[t] += red[t + off]; __syncthreads(); }
  if (t == 0) bsum[blockIdx.x] = red[0];
}

__global__ void scan2_k(int* __restrict__ bsum, int nb) {
  if (threadIdx.x == 0) {
    int run = 0;
    for (int i = 0; i < nb; ++i) { int v = bsum[i]; bsum[i] = run; run += v; }
  }
}

__global__ __launch_bounds__(256) void scan3_k(const int* __restrict__ deg,
                                               const int* __restrict__ bsum,
                                               int* __restrict__ rowptr, int N) {
  __shared__ int tsum[256];
  int base = blockIdx.x * 1024, t = threadIdx.x;
  int v[4]; int s = 0;
#pragma unroll
  for (int j = 0; j < 4; ++j) { int i = base + t * 4 + j; v[j] = (i < N) ? deg[i] : 0; s += v[j]; }
  tsum[t] = s; __syncthreads();
  for (int off = 1; off < 256; off <<= 1) {
    int x = (t >= off) ? tsum[t - off] : 0;
    __syncthreads();
    tsum[t] += x;
    __syncthreads();
  }
  int run = bsum[blockIdx.x] + ((t > 0) ? tsum[t - 1] : 0);
#pragma unroll
  for (int j = 0; j < 4; ++j) {
    int i = base + t * 4 + j;
    if (i < N) rowptr[i] = run;
    run += v[j];
  }
}

__global__ void setval_k(int* __restrict__ p, int v) { *p = v; }

__global__ void copy2_k(const int* __restrict__ a, int* __restrict__ b, int Na,
                        const int* __restrict__ c, int* __restrict__ d, int Nc) {
  int i = blockIdx.x * blockDim.x + threadIdx.x;
  if (i < Na) b[i] = a[i];
  else if (i < Na + Nc) d[i - Na] = c[i - Na];
}

__global__ void scat_k(const int* __restrict__ ei, const int* __restrict__ eu,
                       int* __restrict__ curi, int* __restrict__ srci,
                       int* __restrict__ curu, int* __restrict__ srcu) {
  int e = blockIdx.x * blockDim.x + threadIdx.x;
  if (e < NEDGES) {
    int p = atomicAdd(&curi[ei[e]], 1);
    srci[p] = eu[e];
  } else if (e < 2 * NEDGES) {
    int e2 = e - NEDGES;
    int p = atomicAdd(&curu[eu[e2]], 1);
    srcu[p] = ei[e2];
  }
}

// ---------- fused segment-softmax + gather; wave per dst ----------
// Softmax lane map: lane = (edge slot p = lane>>2, head hh = lane&3); segmented
// butterfly (xor 4,8,16,32) reduces over slots within each head. Exp staged to
// LDS [slot*4+head]; precomputed row byte-offsets staged beside. Gather reads
// its OWN channel-head h = c0/DH. Gather chunked 4-deep (zero-padded slots).
// Output stores are NON-TEMPORAL: agg's own 36MB write stream otherwise evicts
// the hs rows in L2 whose reuse determines FETCH (the measured bottleneck).
template <int W, int DH, typename OUT>
__global__ __launch_bounds__(256) void agg_k(
    const float* __restrict__ elA, const float* __restrict__ erA,
    const int* __restrict__ rpA, const int* __restrict__ srcA,
    const f16* __restrict__ hsA, OUT* __restrict__ outA, int nA,
    const float* __restrict__ elB, const float* __restrict__ erB,
    const int* __restrict__ rpB, const int* __restrict__ srcB,
    const f16* __restrict__ hsB, OUT* __restrict__ outB, int nB) {
  constexpr int CPL = W >> 6;                   // channels per lane
  constexpr int SHIFT = (W == 256) ? 9 : 8;     // log2(W * sizeof(f16))
  constexpr bool OF16 = (sizeof(OUT) == 2);
  __shared__ float alds[4][256];   // [wave][slot*4 + head]
  __shared__ int soff[4][64];      // [wave][slot] = src row byte offset
  int wv = threadIdx.x >> 6;
  int g = blockIdx.x * 4 + wv;
  int lane = threadIdx.x & 63;
  const float* el; const float* er; const int* rp; const int* srcv;
  const f16* hs; OUT* outp; int d;
  if (g < nA)           { el = elA; er = erA; rp = rpA; srcv = srcA; hs = hsA; outp = outA; d = g; }
  else if (g < nA + nB) { el = elB; er = erB; rp = rpB; srcv = srcB; hs = hsB; outp = outB; d = g - nA; }
  else return;
  int s0 = rp[d], s1 = rp[d + 1];
  int deg = s1 - s0;
  int c0 = lane * CPL;
  int h = c0 / DH;
  long obase = (long)d * W + c0;
  if (deg == 0) {
#pragma unroll
    for (int q = 0; q < CPL; ++q) outp[obase + q] = (OUT)0.f;
    return;
  }
  const float NEG = -3.0e38f;
  float acc[CPL];
#pragma unroll
  for (int q = 0; q < CPL; ++q) acc[q] = 0.f;
  float inv;

  if (deg <= 64) {
    int hh = lane & 3, p = lane >> 2;
    float er_h = er[d * 4 + hh];
    float vv[4];
    float vmax = NEG;
#pragma unroll
    for (int j = 0; j < 4; ++j) {
      int slot = j * 16 + p;
      vv[j] = NEG;
      if (slot < deg) {
        int sj = srcv[s0 + slot];
        if (hh == 0) soff[wv][slot] = sj << SHIFT;
        float v = el[sj * 4 + hh] + er_h;
        v = v > 0.f ? v : 0.2f * v;
        vv[j] = v;
        vmax = fmaxf(vmax, v);
      }
    }
#pragma unroll
    for (int off = 4; off < 64; off <<= 1) vmax = fmaxf(vmax, __shfl_xor(vmax, off, 64));
    float ssum = 0.f;
#pragma unroll
    for (int j = 0; j < 4; ++j) {
      int slot = j * 16 + p;
      if (slot < deg) {
        float e = expf(vv[j] - vmax);
        alds[wv][slot * 4 + hh] = e;
        ssum += e;
      } else {
        alds[wv][slot * 4 + hh] = 0.f;       // zero-pad alpha
        if (hh == 0) soff[wv][slot] = 0;     // pad offset -> row 0 (always cached)
      }
    }
#pragma unroll
    for (int off = 4; off < 64; off <<= 1) ssum += __shfl_xor(ssum, off, 64);
    float Sh = __shfl(ssum, (lane & ~3) | h, 64);
    inv = 1.0f / Sh;
    const char* hbase = (const char*)hs + (size_t)c0 * sizeof(f16);
    int degp = (deg + 3) & ~3;
    for (int j = 0; j < degp; j += 4) {
      float aj[4]; int oj[4];
#pragma unroll
      for (int u = 0; u < 4; ++u) {
        aj[u] = alds[wv][(j + u) * 4 + h];
        oj[u] = soff[wv][j + u];
      }
      if constexpr (CPL == 4) {
        f16x4 vj[4];
#pragma unroll
        for (int u = 0; u < 4; ++u)
          vj[u] = *(const f16x4*)(hbase + (size_t)(unsigned)oj[u]);
#pragma unroll
        for (int u = 0; u < 4; ++u) {
          acc[0] += aj[u] * (float)vj[u][0];
          acc[1] += aj[u] * (float)vj[u][1];
          acc[2] += aj[u] * (float)vj[u][2];
          acc[3] += aj[u] * (float)vj[u][3];
        }
      } else {
        f16x2 vj[4];
#pragma unroll
        for (int u = 0; u < 4; ++u)
          vj[u] = *(const f16x2*)(hbase + (size_t)(unsigned)oj[u]);
#pragma unroll
        for (int u = 0; u < 4; ++u) {
          acc[0] += aj[u] * (float)vj[u][0];
          acc[1] += aj[u] * (float)vj[u][1];
        }
      }
    }
  } else {
    // ---- generic fallback (deg > 64): strided two-pass + serial gather ----
    float4 er4 = *(const float4*)&er[d * 4];
    float m0 = NEG, m1 = NEG, m2 = NEG, m3 = NEG;
    for (int k = s0 + lane; k < s1; k += 64) {
      int s = srcv[k];
      float4 e4 = *(const float4*)&el[s * 4];
      float v;
      v = e4.x + er4.x; v = v > 0.f ? v : 0.2f * v; m0 = fmaxf(m0, v);
      v = e4.y + er4.y; v = v > 0.f ? v : 0.2f * v; m1 = fmaxf(m1, v);
      v = e4.z + er4.z; v = v > 0.f ? v : 0.2f * v; m2 = fmaxf(m2, v);
      v = e4.w + er4.w; v = v > 0.f ? v : 0.2f * v; m3 = fmaxf(m3, v);
    }
#pragma unroll
    for (int off = 32; off; off >>= 1) {
      m0 = fmaxf(m0, __shfl_xor(m0, off, 64));
      m1 = fmaxf(m1, __shfl_xor(m1, off, 64));
      m2 = fmaxf(m2, __shfl_xor(m2, off, 64));
      m3 = fmaxf(m3, __shfl_xor(m3, off, 64));
    }
    float S0 = 0.f, S1 = 0.f, S2 = 0.f, S3 = 0.f;
    for (int k = s0 + lane; k < s1; k += 64) {
      int s = srcv[k];
      float4 e4 = *(const float4*)&el[s * 4];
      float v;
      v = e4.x + er4.x; v = v > 0.f ? v : 0.2f * v; S0 += expf(v - m0);
      v = e4.y + er4.y; v = v > 0.f ? v : 0.2f * v; S1 += expf(v - m1);
      v = e4.z + er4.z; v = v > 0.f ? v : 0.2f * v; S2 += expf(v - m2);
      v = e4.w + er4.w; v = v > 0.f ? v : 0.2f * v; S3 += expf(v - m3);
    }
#pragma unroll
    for (int off = 32; off; off >>= 1) {
      S0 += __shfl_xor(S0, off, 64);
      S1 += __shfl_xor(S1, off, 64);
      S2 += __shfl_xor(S2, off, 64);
      S3 += __shfl_xor(S3, off, 64);
    }
    float mh = h == 0 ? m0 : h == 1 ? m1 : h == 2 ? m2 : m3;
    float Sh = h == 0 ? S0 : h == 1 ? S1 : h == 2 ? S2 : S3;
    float erh = h == 0 ? er4.x : h == 1 ? er4.y : h == 2 ? er4.z : er4.w;
    inv = 1.0f / Sh;
    for (int k = s0; k < s1; ++k) {
      int s = srcv[k];
      float v = el[s * 4 + h] + erh; v = v > 0.f ? v : 0.2f * v;
      float a = expf(v - mh);
      const f16* row = &hs[(long)s * W + c0];
      if constexpr (CPL == 4) {
        f16x4 hv = *(const f16x4*)row;
        acc[0] += a * (float)hv[0]; acc[1] += a * (float)hv[1];
        acc[2] += a * (float)hv[2]; acc[3] += a * (float)hv[3];
      } else {
        f16x2 hv = *(const f16x2*)row;
        acc[0] += a * (float)hv[0]; acc[1] += a * (float)hv[1];
      }
    }
  }
  if constexpr (OF16) {
    if constexpr (CPL == 4) {
      f16x4 o = { (f16)(acc[0] * inv), (f16)(acc[1] * inv), (f16)(acc[2] * inv), (f16)(acc[3] * inv) };
      __builtin_nontemporal_store(o, (f16x4*)&outp[obase]);
    } else {
      f16x2 o = { (f16)(acc[0] * inv), (f16)(acc[1] * inv) };
      __builtin_nontemporal_store(o, (f16x2*)&outp[obase]);
    }
  } else {
    if constexpr (CPL == 4) {
      f32x4 o = { acc[0] * inv, acc[1] * inv, acc[2] * inv, acc[3] * inv };
      __builtin_nontemporal_store(o, (f32x4*)&outp[obase]);
    } else {
      f32x2 o = { acc[0] * inv, acc[1] * inv };
      __builtin_nontemporal_store(o, (f32x2*)&outp[obase]);
    }
  }
}

// ---------- BN zero ----------
__global__ void zero2_k(float* __restrict__ a, float* __restrict__ b) {
  int t = threadIdx.x;
  a[t] = 0.f; b[t] = 0.f;
}

// ---------- BN stats (f16 input), both sides ----------
__global__ __launch_bounds__(256) void bn_stats2_k(const f16* __restrict__ xu, float* __restrict__ su, int Nu, int gU,
                                                   const f16* __restrict__ xi, float* __restrict__ si, int Ni) {
  const int C = 256;
  int b = blockIdx.x;
  const f16* x; float* sums; int N; int r0;
  if (b < gU) { x = xu; sums = su; N = Nu; r0 = b * 64; }
  else        { x = xi; sums = si; N = Ni; r0 = (b - gU) * 64; }
  int c = threadIdx.x;
  int r1 = min(r0 + 64, N);
  float s = 0.f, s2 = 0.f;
  for (int r = r0; r < r1; ++r) {
    float v = (float)x[(long)r * C + c];
    s += v; s2 += v * v;
  }
  atomicAdd(&sums[c], s);
  atomicAdd(&sums[C + c], s2);
}

// ---------- fused BN apply + activation -> f16 AND next-layer el/er; block per row ----------
__global__ __launch_bounds__(256) void bn_fused_k(
    const f16* __restrict__ xu, const float* __restrict__ su, const float* __restrict__ gbu,
    f16* __restrict__ yu, int Nu,
    const f16* __restrict__ xi, const float* __restrict__ si, const float* __restrict__ gbi,
    f16* __restrict__ yi, int Ni,
    const float* __restrict__ efu, const float* __restrict__ efiu,   // next-layer folds, K=256
    float* __restrict__ el_u, float* __restrict__ er_u,
    float* __restrict__ el_i, float* __restrict__ er_i, int act) {
  const int Kn = 256;
  __shared__ float xs[256];
  int b = blockIdx.x, t = threadIdx.x;
  const f16* x; const float* sums; const float* gb; f16* y; int n; int N;
  const float* elf; const float* erf; float* el; float* er;
  if (b < Nu) { x = xu; sums = su; gb = gbu; y = yu; n = b; N = Nu; elf = efu;  erf = efiu + 4 * Kn; el = el_u; er = er_u; }
  else        { x = xi; sums = si; gb = gbi; y = yi; n = b - Nu; N = Ni; elf = efiu; erf = efu + 4 * Kn;  el = el_i; er = er_i; }
  long base = (long)n * 256;
  float val = (float)x[base + t];
  float inv_n = 1.0f / (float)N;
  float mean = sums[t] * inv_n;
  float var = sums[256 + t] * inv_n - mean * mean;
  float v = gb[t] * (val - mean) * rsqrtf(var + 1e-5f) + gb[256 + t];
  v = act ? tanhf(v) : (v > 0.f ? v : 0.01f * v);
  y[base + t] = (f16)v;
  xs[t] = v;
  __syncthreads();
  int j = t >> 5, l = t & 31;
  const float* fr = (j < 4) ? (elf + j * Kn) : (erf + (j - 4) * Kn);
  float p = 0.f;
  for (int f = l; f < Kn; f += 32) p += xs[f] * fr[f];
#pragma unroll
  for (int off = 16; off; off >>= 1) p += __shfl_down(p, off, 32);
  if (l == 0) { if (j < 4) el[n * 4 + j] = p; else er[n * 4 + (j - 4)] = p; }
}

extern "C" void kernel_launch(void* const* d_in, const int* in_sizes, int n_in,
                              void* d_out, int out_size, void* d_ws, size_t ws_size,
                              hipStream_t stream) {
  const float* x_user = (const float*)d_in[0];
  const float* x_item = (const float*)d_in[1];
  const int* eu = (const int*)d_in[2];
  const int* ei = (const int*)d_in[3];
  const float *Wm[4][2], *Am[4][2];
  for (int L = 0; L < 4; ++L) {
    Wm[L][0] = (const float*)d_in[4 + L * 4 + 0];
    Am[L][0] = (const float*)d_in[4 + L * 4 + 1];
    Wm[L][1] = (const float*)d_in[4 + L * 4 + 2];
    Am[L][1] = (const float*)d_in[4 + L * 4 + 3];
  }
  const float* bnu = (const float*)d_in[20];
  const float* bni = (const float*)d_in[21];
  float* out = (float*)d_out;

  float* ws = (float*)d_ws;
  size_t o = 0;
  float* el_u = ws + o; o += (size_t)NUSERS * 4;
  float* er_u = ws + o; o += (size_t)NUSERS * 4;
  float* el_i = ws + o; o += (size_t)NITEMS * 4;
  float* er_i = ws + o; o += (size_t)NITEMS * 4;
  float* ef_all[4][2];
  for (int L = 0; L < 4; ++L)
    for (int rl = 0; rl < 2; ++rl) { ef_all[L][rl] = ws + o; o += 2048; }
  float* bns_u = ws + o; o += 512;
  float* bns_i = ws + o; o += 512;
  // f16 buffers (offsets in float units; all 16B aligned)
  f16* hb_u   = (f16*)(ws + o); o += (size_t)NUSERS * 128;
  f16* hb_i   = (f16*)(ws + o); o += (size_t)NITEMS * 128;
  f16* hsb_u  = (f16*)(ws + o); o += (size_t)NUSERS * 128;
  f16* hsb_i  = (f16*)(ws + o); o += (size_t)NITEMS * 128;
  f16* aggh_u = (f16*)(ws + o); o += (size_t)NUSERS * 128;
  f16* aggh_i = (f16*)(ws + o); o += (size_t)NITEMS * 128;
  f16* Bt_all[4][2];
  for (int L = 0; L < 4; ++L) {
    int K = (L == 0) ? 128 : 256;
    int W = (L == 3) ? 128 : 256;
    for (int rl = 0; rl < 2; ++rl) { Bt_all[L][rl] = (f16*)(ws + o); o += (size_t)K * W / 2; }
  }
  // CSR scratch (deg_i/deg_u adjacent => single memset); sizes padded for alignment
  int* deg_i    = (int*)(ws + o); o += NITEMS;
  int* deg_u    = (int*)(ws + o); o += NUSERS;
  int* rowptr_i = (int*)(ws + o); o += NITEMS + 4;
  int* rowptr_u = (int*)(ws + o); o += NUSERS + 4;
  int* cur_i    = (int*)(ws + o); o += NITEMS;
  int* cur_u    = (int*)(ws + o); o += NUSERS;
  int* bsum     = (int*)(ws + o); o += 256;
  int* csrsrc_i = (int*)(ws + o); o += NEDGES + 4;
  int* csrsrc_u = (int*)(ws + o); o += NEDGES + 4;

  const int gE2 = (2 * NEDGES + 255) / 256;
  const int nb_i = (NITEMS + 1023) / 1024;
  const int nb_u = (NUSERS + 1023) / 1024;
  const int gU = (NUSERS + 63) / 64;
  const int gI = (NITEMS + 63) / 64;

  // ---- CSR build (once; edges identical across layers) ----
  hipMemsetAsync(deg_i, 0, (NITEMS + NUSERS) * sizeof(int), stream);
  hist_k<<<dim3(gE2), dim3(256), 0, stream>>>(ei, deg_i, eu, deg_u);
  scan1_k<<<dim3(nb_i), dim3(256), 0, stream>>>(deg_i, bsum, NITEMS);
  scan2_k<<<dim3(1), dim3(64), 0, stream>>>(bsum, nb_i);
  scan3_k<<<dim3(nb_i), dim3(256), 0, stream>>>(deg_i, bsum, rowptr_i, NITEMS);
  setval_k<<<dim3(1), dim3(1), 0, stream>>>(rowptr_i + NITEMS, NEDGES);
  scan1_k<<<dim3(nb_u), dim3(256), 0, stream>>>(deg_u, bsum, NUSERS);
  scan2_k<<<dim3(1), dim3(64), 0, stream>>>(bsum, nb_u);
  scan3_k<<<dim3(nb_u), dim3(256), 0, stream>>>(deg_u, bsum, rowptr_u, NUSERS);
  setval_k<<<dim3(1), dim3(1), 0, stream>>>(rowptr_u + NUSERS, NEDGES);
  copy2_k<<<dim3((NITEMS + NUSERS + 255) / 256), dim3(256), 0, stream>>>(rowptr_i, cur_i, NITEMS, rowptr_u, cur_u, NUSERS);
  scat_k<<<dim3(gE2), dim3(256), 0, stream>>>(ei, eu, cur_i, csrsrc_i, cur_u, csrsrc_u);

  // ---- all layer preps upfront (Bt + el/er folds) ----
  for (int L = 0; L < 4; ++L) {
    int K = (L == 0) ? 128 : 256;
    int dh = (L == 3) ? 32 : 64;
    int W = 4 * dh;
    prep_k<<<dim3((2 * K * W + 255) / 256), dim3(256), 0, stream>>>(
        Wm[L][0], Am[L][0], Bt_all[L][0], ef_all[L][0],
        Wm[L][1], Am[L][1], Bt_all[L][1], ef_all[L][1], K, W, dh);
  }

  // layer-0 inputs -> f16; layer-0 el/er
  xcvt_k<<<dim3(((NUSERS + NITEMS) * 128 + 255) / 256), dim3(256), 0, stream>>>(
      x_user, hb_u, (long)NUSERS * 128, x_item, hb_i, (long)NITEMS * 128);
  eler_k<<<dim3(NUSERS + NITEMS), dim3(256), 0, stream>>>(
      hb_u, ef_all[0][0], ef_all[0][1], el_u, er_u, hb_i, el_i, er_i, 128);

  int K = 128;
  const int gAgg = (NITEMS + NUSERS + 3) / 4;
  const int gya = (NUSERS + 127) / 128, gyb = (NITEMS + 127) / 128;
  for (int L = 0; L < 4; ++L) {
    if (L < 3) {
      hgemm_k<256><<<dim3(gya + gyb), dim3(256), 0, stream>>>(
          hb_u, Bt_all[L][0], hsb_u, NUSERS, gya, hb_i, Bt_all[L][1], hsb_i, NITEMS, K);
      agg_k<256, 64, f16><<<dim3(gAgg), dim3(256), 0, stream>>>(
          el_u, er_i, rowptr_i, csrsrc_i, hsb_u, aggh_i, NITEMS,
          el_i, er_u, rowptr_u, csrsrc_u, hsb_i, aggh_u, NUSERS);
      zero2_k<<<dim3(1), dim3(512), 0, stream>>>(bns_u, bns_i);
      bn_stats2_k<<<dim3(gU + gI), dim3(256), 0, stream>>>(aggh_u, bns_u, NUSERS, gU, aggh_i, bns_i, NITEMS);
      bn_fused_k<<<dim3(NUSERS + NITEMS), dim3(256), 0, stream>>>(
          aggh_u, bns_u, bnu + L * 512, hb_u, NUSERS,
          aggh_i, bns_i, bni + L * 512, hb_i, NITEMS,
          ef_all[L + 1][0], ef_all[L + 1][1],
          el_u, er_u, el_i, er_i, L == 2);
      K = 256;
    } else {
      hgemm_k<128><<<dim3(gya + gyb), dim3(256), 0, stream>>>(
          hb_u, Bt_all[L][0], hsb_u, NUSERS, gya, hb_i, Bt_all[L][1], hsb_i, NITEMS, K);
      agg_k<128, 32, float><<<dim3(gAgg), dim3(256), 0, stream>>>(
          el_u, er_i, rowptr_i, csrsrc_i, hsb_u, out + (size_t)NUSERS * 128, NITEMS,
          el_i, er_u, rowptr_u, csrsrc_u, hsb_i, out, NUSERS);
    }
  }
}

// Round 4
// 908.627 us; speedup vs baseline: 1.1413x; 1.0688x over previous
//
#include <hip/hip_runtime.h>

#define NUSERS 50000
#define NITEMS 20000
#define NEDGES 400000

typedef _Float16 f16;
typedef __attribute__((ext_vector_type(8))) _Float16 f16x8;
typedef __attribute__((ext_vector_type(4))) _Float16 f16x4;
typedef __attribute__((ext_vector_type(2))) _Float16 f16x2;
typedef __attribute__((ext_vector_type(4))) float f32x4;
typedef __attribute__((ext_vector_type(2))) float f32x2;

// ---------- prep: LDS-tiled weight transpose->f16 (coalesced both sides)
// + folded el/er projections; both relations in one launch ----------
__global__ __launch_bounds__(256) void prep2_k(
    const float* __restrict__ Wa, const float* __restrict__ Aa,
    f16* __restrict__ Bta, float* __restrict__ efa,
    const float* __restrict__ Wb, const float* __restrict__ Ab,
    f16* __restrict__ Btb, float* __restrict__ efb,
    int K, int Nw, int dh) {
  __shared__ float lds[32][33];
  int ntile = (K >> 5) * (Nw >> 5);
  int b = blockIdx.x, t = threadIdx.x;
  if (b < 2 * ntile) {
    const float* W = (b < ntile) ? Wa : Wb;
    f16* Bt = (b < ntile) ? Bta : Btb;
    int tt = (b < ntile) ? b : b - ntile;
    int ntc = Nw >> 5;
    int tr = tt / ntc, tc = tt - tr * ntc;
    int tx = t & 31, ty = t >> 5;
#pragma unroll
    for (int p = 0; p < 4; ++p) {
      int k = tr * 32 + ty + p * 8;
      int n = tc * 32 + tx;
      lds[ty + p * 8][tx] = W[(long)k * Nw + n];
    }
    __syncthreads();
#pragma unroll
    for (int p = 0; p < 4; ++p) {
      int n = tc * 32 + ty + p * 8;
      int k = tr * 32 + tx;
      Bt[(long)n * K + k] = (f16)lds[tx][ty + p * 8];
    }
  } else {
    int idx = (b - 2 * ntile) * 256 + t;
    if (idx >= 2 * K * 8) return;
    const float* W = (idx < K * 8) ? Wa : Wb;
    const float* A = (idx < K * 8) ? Aa : Ab;
    float* ef = (idx < K * 8) ? efa : efb;
    int t2 = (idx < K * 8) ? idx : idx - K * 8;
    int j = t2 / (K * 4);
    int r = t2 - j * K * 4;
    int h = r / K, f = r - h * K;
    const float* Aj = A + j * Nw;   // A[j], shape [4,dh], Nw = 4*dh
    float s = 0.f;
    for (int d = 0; d < dh; ++d) s += W[f * Nw + h * dh + d] * Aj[h * dh + d];
    ef[j * 4 * K + h * K + f] = s;
  }
}

// ---------- f16 MFMA GEMM, user+item fused: C = A[M,K] @ Bt[N,K]^T ----------
__global__ __launch_bounds__(256) void hgemm2_k(const f16* __restrict__ Aa, const f16* __restrict__ Bta,
                                                f16* __restrict__ Ca, int Ma, int gya,
                                                const f16* __restrict__ Ab, const f16* __restrict__ Btb,
                                                f16* __restrict__ Cb, int Mb,
                                                int N, int K) {
  __shared__ f16 As[128 * 32];
  __shared__ f16 Bs[128 * 32];
  int by = blockIdx.y;
  const f16* A; const f16* Bt; f16* C; int M; int row0;
  if (by < gya) { A = Aa; Bt = Bta; C = Ca; M = Ma; row0 = by * 128; }
  else          { A = Ab; Bt = Btb; C = Cb; M = Mb; row0 = (by - gya) * 128; }
  int tid = threadIdx.x;
  int col0 = blockIdx.x * 128;
  int lane = tid & 63, wv = tid >> 6;
  int wr = (wv & 1) * 64, wc = (wv >> 1) * 64;
  int l16 = lane & 15, q = lane >> 4;
  f32x4 acc[4][4] = {};
  int r = tid >> 2, c8 = (tid & 3) * 8;
  for (int k0 = 0; k0 < K; k0 += 32) {
    int ra = min(row0 + r, M - 1);
    uint4 va = *(const uint4*)&A[(long)ra * K + k0 + c8];
    int ra2 = min(row0 + r + 64, M - 1);
    uint4 va2 = *(const uint4*)&A[(long)ra2 * K + k0 + c8];
    uint4 vb = *(const uint4*)&Bt[(long)(col0 + r) * K + k0 + c8];
    uint4 vb2 = *(const uint4*)&Bt[(long)(col0 + r + 64) * K + k0 + c8];
    *(uint4*)&As[r * 32 + c8] = va;
    *(uint4*)&As[(r + 64) * 32 + c8] = va2;
    *(uint4*)&Bs[r * 32 + c8] = vb;
    *(uint4*)&Bs[(r + 64) * 32 + c8] = vb2;
    __syncthreads();
    f16x8 af[4], bfr[4];
#pragma unroll
    for (int i = 0; i < 4; ++i) {
      af[i] = *(const f16x8*)&As[(wr + i * 16 + l16) * 32 + q * 8];
      bfr[i] = *(const f16x8*)&Bs[(wc + i * 16 + l16) * 32 + q * 8];
    }
#pragma unroll
    for (int i = 0; i < 4; ++i)
#pragma unroll
      for (int j = 0; j < 4; ++j)
        acc[i][j] = __builtin_amdgcn_mfma_f32_16x16x32_f16(af[i], bfr[j], acc[i][j], 0, 0, 0);
    __syncthreads();
  }
#pragma unroll
  for (int i = 0; i < 4; ++i) {
#pragma unroll
    for (int reg = 0; reg < 4; ++reg) {
      int rr = row0 + wr + i * 16 + q * 4 + reg;
      if (rr < M) {
#pragma unroll
        for (int j = 0; j < 4; ++j)
          C[(long)rr * N + col0 + wc + j * 16 + l16] = (f16)acc[i][j][reg];
      }
    }
  }
}

// ---------- layer-0: fused f32->f16 convert + el/er via folds; block per node ----------
__global__ __launch_bounds__(256) void eler2_k(
    const float* __restrict__ xu, f16* __restrict__ hbu,
    const float* __restrict__ ef_ui, const float* __restrict__ ef_iu,
    float* __restrict__ el_u, float* __restrict__ er_u,
    const float* __restrict__ xi, f16* __restrict__ hbi,
    float* __restrict__ el_i, float* __restrict__ er_i, int K) {
  __shared__ float xs[256];
  int b = blockIdx.x, t = threadIdx.x;
  const float* x; f16* hb; const float* elf; const float* erf; float* el; float* er; int n;
  if (b < NUSERS) { x = xu; hb = hbu; elf = ef_ui; erf = ef_iu + 4 * K; el = el_u; er = er_u; n = b; }
  else            { x = xi; hb = hbi; elf = ef_iu; erf = ef_ui + 4 * K; el = el_i; er = er_i; n = b - NUSERS; }
  if (t < K) {
    float v = x[(long)n * K + t];
    hb[(long)n * K + t] = (f16)v;
    xs[t] = v;
  }
  __syncthreads();
  int j = t >> 5, l = t & 31;
  const float* fr = (j < 4) ? (elf + j * K) : (erf + (j - 4) * K);
  float p = 0.f;
  for (int f = l; f < K; f += 32) p += xs[f] * fr[f];
#pragma unroll
  for (int off = 16; off; off >>= 1) p += __shfl_down(p, off, 32);
  if (l == 0) { if (j < 4) el[n * 4 + j] = p; else er[n * 4 + (j - 4)] = p; }
}

// ---------- CSR build ----------
__global__ void hist_k(const int* __restrict__ ei, int* __restrict__ degi,
                       const int* __restrict__ eu, int* __restrict__ degu) {
  int e = blockIdx.x * blockDim.x + threadIdx.x;
  if (e < NEDGES) atomicAdd(&degi[ei[e]], 1);
  else if (e < 2 * NEDGES) atomicAdd(&degu[eu[e - NEDGES]], 1);
}

__global__ __launch_bounds__(256) void scan1_k(const int* __restrict__ deg,
                                               int* __restrict__ bsum, int N) {
  __shared__ int red[256];
  int base = blockIdx.x * 1024, t = threadIdx.x;
  int s = 0;
#pragma unroll
  for (int j = 0; j < 4; ++j) { int i = base + t * 4 + j; s += (i < N) ? deg[i] : 0; }
  red[t] = s; __syncthreads();
  for (int off = 128; off; off >>= 1) { if (t < off) red[t] += red[t + off]; __syncthreads(); }
  if (t == 0) bsum[blockIdx.x] = red[0];
}

// exclusive block-sum scan + writes rowptr[N]=NEDGES terminator (folds old setval_k)
__global__ void scan2_k(int* __restrict__ bsum, int nb, int* __restrict__ endp, int endv) {
  if (threadIdx.x == 0) {
    int run = 0;
    for (int i = 0; i < nb; ++i) { int v = bsum[i]; bsum[i] = run; run += v; }
    *endp = endv;
  }
}

__global__ __launch_bounds__(256) void scan3_k(const int* __restrict__ deg,
                                               const int* __restrict__ bsum,
                                               int* __restrict__ rowptr, int N) {
  __shared__ int tsum[256];
  int base = blockIdx.x * 1024, t = threadIdx.x;
  int v[4]; int s = 0;
#pragma unroll
  for (int j = 0; j < 4; ++j) { int i = base + t * 4 + j; v[j] = (i < N) ? deg[i] : 0; s += v[j]; }
  tsum[t] = s; __syncthreads();
  for (int off = 1; off < 256; off <<= 1) {
    int x = (t >= off) ? tsum[t - off] : 0;
    __syncthreads();
    tsum[t] += x;
    __syncthreads();
  }
  int run = bsum[blockIdx.x] + ((t > 0) ? tsum[t - 1] : 0);
#pragma unroll
  for (int j = 0; j < 4; ++j) {
    int i = base + t * 4 + j;
    if (i < N) rowptr[i] = run;
    run += v[j];
  }
}

__global__ void copy2_k(const int* __restrict__ a, int* __restrict__ b, int Na,
                        const int* __restrict__ c, int* __restrict__ d, int Nc) {
  int i = blockIdx.x * blockDim.x + threadIdx.x;
  if (i < Na) b[i] = a[i];
  else if (i < Na + Nc) d[i - Na] = c[i - Na];
}

__global__ void scat_k(const int* __restrict__ ei, const int* __restrict__ eu,
                       int* __restrict__ curi, int* __restrict__ srci,
                       int* __restrict__ curu, int* __restrict__ srcu) {
  int e = blockIdx.x * blockDim.x + threadIdx.x;
  if (e < NEDGES) {
    int p = atomicAdd(&curi[ei[e]], 1);
    srci[p] = eu[e];
  } else if (e < 2 * NEDGES) {
    int e2 = e - NEDGES;
    int p = atomicAdd(&curu[eu[e2]], 1);
    srcu[p] = ei[e2];
  }
}

// ---------- fused segment-softmax + gather; wave per dst ----------
// Softmax lane map: lane = (edge slot p = lane>>2, head hh = lane&3); segmented
// butterfly (xor 4,8,16,32) reduces over slots within each head. Exp staged to
// LDS [slot*4+head]; precomputed row byte-offsets staged beside. Gather reads
// its OWN channel-head h = c0/DH. Gather chunked 4-deep (zero-padded slots).
// Output stores NON-TEMPORAL (measured: FETCH -4MB, keeps hs rows in L2).
template <int W, int DH, typename OUT>
__global__ __launch_bounds__(256) void agg_k(
    const float* __restrict__ elA, const float* __restrict__ erA,
    const int* __restrict__ rpA, const int* __restrict__ srcA,
    const f16* __restrict__ hsA, OUT* __restrict__ outA, int nA,
    const float* __restrict__ elB, const float* __restrict__ erB,
    const int* __restrict__ rpB, const int* __restrict__ srcB,
    const f16* __restrict__ hsB, OUT* __restrict__ outB, int nB) {
  constexpr int CPL = W >> 6;                   // channels per lane
  constexpr int SHIFT = (W == 256) ? 9 : 8;     // log2(W * sizeof(f16))
  constexpr bool OF16 = (sizeof(OUT) == 2);
  __shared__ float alds[4][256];   // [wave][slot*4 + head]
  __shared__ int soff[4][64];      // [wave][slot] = src row byte offset
  int wv = threadIdx.x >> 6;
  int g = blockIdx.x * 4 + wv;
  int lane = threadIdx.x & 63;
  const float* el; const float* er; const int* rp; const int* srcv;
  const f16* hs; OUT* outp; int d;
  if (g < nA)           { el = elA; er = erA; rp = rpA; srcv = srcA; hs = hsA; outp = outA; d = g; }
  else if (g < nA + nB) { el = elB; er = erB; rp = rpB; srcv = srcB; hs = hsB; outp = outB; d = g - nA; }
  else return;
  int s0 = rp[d], s1 = rp[d + 1];
  int deg = s1 - s0;
  int c0 = lane * CPL;
  int h = c0 / DH;
  long obase = (long)d * W + c0;
  if (deg == 0) {
#pragma unroll
    for (int q = 0; q < CPL; ++q) outp[obase + q] = (OUT)0.f;
    return;
  }
  const float NEG = -3.0e38f;
  float acc[CPL];
#pragma unroll
  for (int q = 0; q < CPL; ++q) acc[q] = 0.f;
  float inv;

  if (deg <= 64) {
    int hh = lane & 3, p = lane >> 2;
    float er_h = er[d * 4 + hh];
    float vv[4];
    float vmax = NEG;
#pragma unroll
    for (int j = 0; j < 4; ++j) {
      int slot = j * 16 + p;
      vv[j] = NEG;
      if (slot < deg) {
        int sj = srcv[s0 + slot];
        if (hh == 0) soff[wv][slot] = sj << SHIFT;
        float v = el[sj * 4 + hh] + er_h;
        v = v > 0.f ? v : 0.2f * v;
        vv[j] = v;
        vmax = fmaxf(vmax, v);
      }
    }
#pragma unroll
    for (int off = 4; off < 64; off <<= 1) vmax = fmaxf(vmax, __shfl_xor(vmax, off, 64));
    float ssum = 0.f;
#pragma unroll
    for (int j = 0; j < 4; ++j) {
      int slot = j * 16 + p;
      if (slot < deg) {
        float e = expf(vv[j] - vmax);
        alds[wv][slot * 4 + hh] = e;
        ssum += e;
      } else {
        alds[wv][slot * 4 + hh] = 0.f;       // zero-pad alpha
        if (hh == 0) soff[wv][slot] = 0;     // pad offset -> row 0 (always cached)
      }
    }
#pragma unroll
    for (int off = 4; off < 64; off <<= 1) ssum += __shfl_xor(ssum, off, 64);
    float Sh = __shfl(ssum, (lane & ~3) | h, 64);
    inv = 1.0f / Sh;
    const char* hbase = (const char*)hs + (size_t)c0 * sizeof(f16);
    int degp = (deg + 3) & ~3;
    for (int j = 0; j < degp; j += 4) {
      float aj[4]; int oj[4];
#pragma unroll
      for (int u = 0; u < 4; ++u) {
        aj[u] = alds[wv][(j + u) * 4 + h];
        oj[u] = soff[wv][j + u];
      }
      if constexpr (CPL == 4) {
        f16x4 vj[4];
#pragma unroll
        for (int u = 0; u < 4; ++u)
          vj[u] = *(const f16x4*)(hbase + (size_t)(unsigned)oj[u]);
#pragma unroll
        for (int u = 0; u < 4; ++u) {
          acc[0] += aj[u] * (float)vj[u][0];
          acc[1] += aj[u] * (float)vj[u][1];
          acc[2] += aj[u] * (float)vj[u][2];
          acc[3] += aj[u] * (float)vj[u][3];
        }
      } else {
        f16x2 vj[4];
#pragma unroll
        for (int u = 0; u < 4; ++u)
          vj[u] = *(const f16x2*)(hbase + (size_t)(unsigned)oj[u]);
#pragma unroll
        for (int u = 0; u < 4; ++u) {
          acc[0] += aj[u] * (float)vj[u][0];
          acc[1] += aj[u] * (float)vj[u][1];
        }
      }
    }
  } else {
    // ---- generic fallback (deg > 64): strided two-pass + serial gather ----
    float4 er4 = *(const float4*)&er[d * 4];
    float m0 = NEG, m1 = NEG, m2 = NEG, m3 = NEG;
    for (int k = s0 + lane; k < s1; k += 64) {
      int s = srcv[k];
      float4 e4 = *(const float4*)&el[s * 4];
      float v;
      v = e4.x + er4.x; v = v > 0.f ? v : 0.2f * v; m0 = fmaxf(m0, v);
      v = e4.y + er4.y; v = v > 0.f ? v : 0.2f * v; m1 = fmaxf(m1, v);
      v = e4.z + er4.z; v = v > 0.f ? v : 0.2f * v; m2 = fmaxf(m2, v);
      v = e4.w + er4.w; v = v > 0.f ? v : 0.2f * v; m3 = fmaxf(m3, v);
    }
#pragma unroll
    for (int off = 32; off; off >>= 1) {
      m0 = fmaxf(m0, __shfl_xor(m0, off, 64));
      m1 = fmaxf(m1, __shfl_xor(m1, off, 64));
      m2 = fmaxf(m2, __shfl_xor(m2, off, 64));
      m3 = fmaxf(m3, __shfl_xor(m3, off, 64));
    }
    float S0 = 0.f, S1 = 0.f, S2 = 0.f, S3 = 0.f;
    for (int k = s0 + lane; k < s1; k += 64) {
      int s = srcv[k];
      float4 e4 = *(const float4*)&el[s * 4];
      float v;
      v = e4.x + er4.x; v = v > 0.f ? v : 0.2f * v; S0 += expf(v - m0);
      v = e4.y + er4.y; v = v > 0.f ? v : 0.2f * v; S1 += expf(v - m1);
      v = e4.z + er4.z; v = v > 0.f ? v : 0.2f * v; S2 += expf(v - m2);
      v = e4.w + er4.w; v = v > 0.f ? v : 0.2f * v; S3 += expf(v - m3);
    }
#pragma unroll
    for (int off = 32; off; off >>= 1) {
      S0 += __shfl_xor(S0, off, 64);
      S1 += __shfl_xor(S1, off, 64);
      S2 += __shfl_xor(S2, off, 64);
      S3 += __shfl_xor(S3, off, 64);
    }
    float mh = h == 0 ? m0 : h == 1 ? m1 : h == 2 ? m2 : m3;
    float Sh = h == 0 ? S0 : h == 1 ? S1 : h == 2 ? S2 : S3;
    float erh = h == 0 ? er4.x : h == 1 ? er4.y : h == 2 ? er4.z : er4.w;
    inv = 1.0f / Sh;
    for (int k = s0; k < s1; ++k) {
      int s = srcv[k];
      float v = el[s * 4 + h] + erh; v = v > 0.f ? v : 0.2f * v;
      float a = expf(v - mh);
      const f16* row = &hs[(long)s * W + c0];
      if constexpr (CPL == 4) {
        f16x4 hv = *(const f16x4*)row;
        acc[0] += a * (float)hv[0]; acc[1] += a * (float)hv[1];
        acc[2] += a * (float)hv[2]; acc[3] += a * (float)hv[3];
      } else {
        f16x2 hv = *(const f16x2*)row;
        acc[0] += a * (float)hv[0]; acc[1] += a * (float)hv[1];
      }
    }
  }
  if constexpr (OF16) {
    if constexpr (CPL == 4) {
      f16x4 o = { (f16)(acc[0] * inv), (f16)(acc[1] * inv), (f16)(acc[2] * inv), (f16)(acc[3] * inv) };
      __builtin_nontemporal_store(o, (f16x4*)&outp[obase]);
    } else {
      f16x2 o = { (f16)(acc[0] * inv), (f16)(acc[1] * inv) };
      __builtin_nontemporal_store(o, (f16x2*)&outp[obase]);
    }
  } else {
    if constexpr (CPL == 4) {
      f32x4 o = { acc[0] * inv, acc[1] * inv, acc[2] * inv, acc[3] * inv };
      __builtin_nontemporal_store(o, (f32x4*)&outp[obase]);
    } else {
      f32x2 o = { acc[0] * inv, acc[1] * inv };
      __builtin_nontemporal_store(o, (f32x2*)&outp[obase]);
    }
  }
}

// ---------- BN stats (f16 input), both sides; per-layer sum regions ----------
__global__ __launch_bounds__(256) void bn_stats2_k(const f16* __restrict__ xu, float* __restrict__ su, int Nu, int gU,
                                                   const f16* __restrict__ xi, float* __restrict__ si, int Ni) {
  const int C = 256;
  int b = blockIdx.x;
  const f16* x; float* sums; int N; int r0;
  if (b < gU) { x = xu; sums = su; N = Nu; r0 = b * 64; }
  else        { x = xi; sums = si; N = Ni; r0 = (b - gU) * 64; }
  int c = threadIdx.x;
  int r1 = min(r0 + 64, N);
  float s = 0.f, s2 = 0.f;
  for (int r = r0; r < r1; ++r) {
    float v = (float)x[(long)r * C + c];
    s += v; s2 += v * v;
  }
  atomicAdd(&sums[c], s);
  atomicAdd(&sums[C + c], s2);
}

// ---------- fused BN apply + activation -> f16 AND next-layer el/er; block per row ----------
__global__ __launch_bounds__(256) void bn_fused_k(
    const f16* __restrict__ xu, const float* __restrict__ su, const float* __restrict__ gbu,
    f16* __restrict__ yu, int Nu,
    const f16* __restrict__ xi, const float* __restrict__ si, const float* __restrict__ gbi,
    f16* __restrict__ yi, int Ni,
    const float* __restrict__ efu, const float* __restrict__ efiu,   // next-layer folds, K=256
    float* __restrict__ el_u, float* __restrict__ er_u,
    float* __restrict__ el_i, float* __restrict__ er_i, int act) {
  const int Kn = 256;
  __shared__ float xs[256];
  int b = blockIdx.x, t = threadIdx.x;
  const f16* x; const float* sums; const float* gb; f16* y; int n; int N;
  const float* elf; const float* erf; float* el; float* er;
  if (b < Nu) { x = xu; sums = su; gb = gbu; y = yu; n = b; N = Nu; elf = efu;  erf = efiu + 4 * Kn; el = el_u; er = er_u; }
  else        { x = xi; sums = si; gb = gbi; y = yi; n = b - Nu; N = Ni; elf = efiu; erf = efu + 4 * Kn;  el = el_i; er = er_i; }
  long base = (long)n * 256;
  float val = (float)x[base + t];
  float inv_n = 1.0f / (float)N;
  float mean = sums[t] * inv_n;
  float var = sums[256 + t] * inv_n - mean * mean;
  float v = gb[t] * (val - mean) * rsqrtf(var + 1e-5f) + gb[256 + t];
  v = act ? tanhf(v) : (v > 0.f ? v : 0.01f * v);
  y[base + t] = (f16)v;
  xs[t] = v;
  __syncthreads();
  int j = t >> 5, l = t & 31;
  const float* fr = (j < 4) ? (elf + j * Kn) : (erf + (j - 4) * Kn);
  float p = 0.f;
  for (int f = l; f < Kn; f += 32) p += xs[f] * fr[f];
#pragma unroll
  for (int off = 16; off; off >>= 1) p += __shfl_down(p, off, 32);
  if (l == 0) { if (j < 4) el[n * 4 + j] = p; else er[n * 4 + (j - 4)] = p; }
}

extern "C" void kernel_launch(void* const* d_in, const int* in_sizes, int n_in,
                              void* d_out, int out_size, void* d_ws, size_t ws_size,
                              hipStream_t stream) {
  const float* x_user = (const float*)d_in[0];
  const float* x_item = (const float*)d_in[1];
  const int* eu = (const int*)d_in[2];
  const int* ei = (const int*)d_in[3];
  const float *Wm[4][2], *Am[4][2];
  for (int L = 0; L < 4; ++L) {
    Wm[L][0] = (const float*)d_in[4 + L * 4 + 0];
    Am[L][0] = (const float*)d_in[4 + L * 4 + 1];
    Wm[L][1] = (const float*)d_in[4 + L * 4 + 2];
    Am[L][1] = (const float*)d_in[4 + L * 4 + 3];
  }
  const float* bnu = (const float*)d_in[20];
  const float* bni = (const float*)d_in[21];
  float* out = (float*)d_out;

  float* ws = (float*)d_ws;
  size_t o = 0;
  float* el_u = ws + o; o += (size_t)NUSERS * 4;
  float* er_u = ws + o; o += (size_t)NUSERS * 4;
  float* el_i = ws + o; o += (size_t)NITEMS * 4;
  float* er_i = ws + o; o += (size_t)NITEMS * 4;
  float* ef_all[4][2];
  for (int L = 0; L < 4; ++L)
    for (int rl = 0; rl < 2; ++rl) { ef_all[L][rl] = ws + o; o += 2048; }
  // f16 buffers (offsets in float units; all 16B aligned)
  f16* hb_u   = (f16*)(ws + o); o += (size_t)NUSERS * 128;
  f16* hb_i   = (f16*)(ws + o); o += (size_t)NITEMS * 128;
  f16* hsb_u  = (f16*)(ws + o); o += (size_t)NUSERS * 128;
  f16* hsb_i  = (f16*)(ws + o); o += (size_t)NITEMS * 128;
  f16* aggh_u = (f16*)(ws + o); o += (size_t)NUSERS * 128;
  f16* aggh_i = (f16*)(ws + o); o += (size_t)NITEMS * 128;
  f16* Bt_all[4][2];
  for (int L = 0; L < 4; ++L) {
    int K = (L == 0) ? 128 : 256;
    int W = (L == 3) ? 128 : 256;
    for (int rl = 0; rl < 2; ++rl) { Bt_all[L][rl] = (f16*)(ws + o); o += (size_t)K * W / 2; }
  }
  // BN sums (3 layers x (512u + 512i)) + CSR deg: contiguous => single memset
  float* bns_all = ws + o; o += 3 * 1024;
  int* deg_i    = (int*)(ws + o); o += NITEMS;
  int* deg_u    = (int*)(ws + o); o += NUSERS;
  int* rowptr_i = (int*)(ws + o); o += NITEMS + 4;
  int* rowptr_u = (int*)(ws + o); o += NUSERS + 4;
  int* cur_i    = (int*)(ws + o); o += NITEMS;
  int* cur_u    = (int*)(ws + o); o += NUSERS;
  int* bsum     = (int*)(ws + o); o += 256;
  int* csrsrc_i = (int*)(ws + o); o += NEDGES + 4;
  int* csrsrc_u = (int*)(ws + o); o += NEDGES + 4;

  const int gE2 = (2 * NEDGES + 255) / 256;
  const int nb_i = (NITEMS + 1023) / 1024;
  const int nb_u = (NUSERS + 1023) / 1024;
  const int gU = (NUSERS + 63) / 64;
  const int gI = (NITEMS + 63) / 64;

  // ---- zero BN sums + deg in one memset; CSR build (once) ----
  hipMemsetAsync(bns_all, 0, (3 * 1024 + NITEMS + NUSERS) * sizeof(float), stream);
  hist_k<<<dim3(gE2), dim3(256), 0, stream>>>(ei, deg_i, eu, deg_u);
  scan1_k<<<dim3(nb_i), dim3(256), 0, stream>>>(deg_i, bsum, NITEMS);
  scan2_k<<<dim3(1), dim3(64), 0, stream>>>(bsum, nb_i, rowptr_i + NITEMS, NEDGES);
  scan3_k<<<dim3(nb_i), dim3(256), 0, stream>>>(deg_i, bsum, rowptr_i, NITEMS);
  scan1_k<<<dim3(nb_u), dim3(256), 0, stream>>>(deg_u, bsum, NUSERS);
  scan2_k<<<dim3(1), dim3(64), 0, stream>>>(bsum, nb_u, rowptr_u + NUSERS, NEDGES);
  scan3_k<<<dim3(nb_u), dim3(256), 0, stream>>>(deg_u, bsum, rowptr_u, NUSERS);
  copy2_k<<<dim3((NITEMS + NUSERS + 255) / 256), dim3(256), 0, stream>>>(rowptr_i, cur_i, NITEMS, rowptr_u, cur_u, NUSERS);
  scat_k<<<dim3(gE2), dim3(256), 0, stream>>>(ei, eu, cur_i, csrsrc_i, cur_u, csrsrc_u);

  // ---- all layer preps upfront (tiled Bt transpose + el/er folds) ----
  for (int L = 0; L < 4; ++L) {
    int K = (L == 0) ? 128 : 256;
    int dh = (L == 3) ? 32 : 64;
    int W = 4 * dh;
    int ntile2 = 2 * (K / 32) * (W / 32);
    int gef = (2 * K * 8 + 255) / 256;
    prep2_k<<<dim3(ntile2 + gef), dim3(256), 0, stream>>>(
        Wm[L][0], Am[L][0], Bt_all[L][0], ef_all[L][0],
        Wm[L][1], Am[L][1], Bt_all[L][1], ef_all[L][1], K, W, dh);
  }

  // layer-0: fused f32->f16 convert + el/er
  eler2_k<<<dim3(NUSERS + NITEMS), dim3(256), 0, stream>>>(
      x_user, hb_u, ef_all[0][0], ef_all[0][1], el_u, er_u,
      x_item, hb_i, el_i, er_i, 128);

  int K = 128;
  const int gAgg = (NITEMS + NUSERS + 3) / 4;
  const int gya = (NUSERS + 127) / 128, gyb = (NITEMS + 127) / 128;
  for (int L = 0; L < 4; ++L) {
    const int dh = (L == 3) ? 32 : 64;
    const int W = 4 * dh;

    hgemm2_k<<<dim3(W / 128, gya + gyb), dim3(256), 0, stream>>>(
        hb_u, Bt_all[L][0], hsb_u, NUSERS, gya, hb_i, Bt_all[L][1], hsb_i, NITEMS, W, K);

    if (L < 3) {
      float* su = bns_all + (size_t)L * 1024;
      float* si = su + 512;
      agg_k<256, 64, f16><<<dim3(gAgg), dim3(256), 0, stream>>>(
          el_u, er_i, rowptr_i, csrsrc_i, hsb_u, aggh_i, NITEMS,
          el_i, er_u, rowptr_u, csrsrc_u, hsb_i, aggh_u, NUSERS);
      bn_stats2_k<<<dim3(gU + gI), dim3(256), 0, stream>>>(aggh_u, su, NUSERS, gU, aggh_i, si, NITEMS);
      bn_fused_k<<<dim3(NUSERS + NITEMS), dim3(256), 0, stream>>>(
          aggh_u, su, bnu + L * 512, hb_u, NUSERS,
          aggh_i, si, bni + L * 512, hb_i, NITEMS,
          ef_all[L + 1][0], ef_all[L + 1][1],
          el_u, er_u, el_i, er_i, L == 2);
      K = 256;
    } else {
      agg_k<128, 32, float><<<dim3(gAgg), dim3(256), 0, stream>>>(
          el_u, er_i, rowptr_i, csrsrc_i, hsb_u, out + (size_t)NUSERS * 128, NITEMS,
          el_i, er_u, rowptr_u, csrsrc_u, hsb_i, out, NUSERS);
    }
  }
}

// Round 5
// 852.356 us; speedup vs baseline: 1.2167x; 1.0660x over previous
//
#include <hip/hip_runtime.h>

#define NUSERS 50000
#define NITEMS 20000
#define NEDGES 400000

typedef _Float16 f16;
typedef __attribute__((ext_vector_type(8))) _Float16 f16x8;
typedef __attribute__((ext_vector_type(4))) _Float16 f16x4;
typedef __attribute__((ext_vector_type(2))) _Float16 f16x2;
typedef __attribute__((ext_vector_type(4))) float f32x4;
typedef __attribute__((ext_vector_type(2))) float f32x2;

// ---------- prep: LDS-tiled weight transpose->f16 (coalesced both sides)
// + folded el/er projections; both relations in one launch ----------
__global__ __launch_bounds__(256) void prep2_k(
    const float* __restrict__ Wa, const float* __restrict__ Aa,
    f16* __restrict__ Bta, float* __restrict__ efa,
    const float* __restrict__ Wb, const float* __restrict__ Ab,
    f16* __restrict__ Btb, float* __restrict__ efb,
    int K, int Nw, int dh) {
  __shared__ float lds[32][33];
  int ntile = (K >> 5) * (Nw >> 5);
  int b = blockIdx.x, t = threadIdx.x;
  if (b < 2 * ntile) {
    const float* W = (b < ntile) ? Wa : Wb;
    f16* Bt = (b < ntile) ? Bta : Btb;
    int tt = (b < ntile) ? b : b - ntile;
    int ntc = Nw >> 5;
    int tr = tt / ntc, tc = tt - tr * ntc;
    int tx = t & 31, ty = t >> 5;
#pragma unroll
    for (int p = 0; p < 4; ++p) {
      int k = tr * 32 + ty + p * 8;
      int n = tc * 32 + tx;
      lds[ty + p * 8][tx] = W[(long)k * Nw + n];
    }
    __syncthreads();
#pragma unroll
    for (int p = 0; p < 4; ++p) {
      int n = tc * 32 + ty + p * 8;
      int k = tr * 32 + tx;
      Bt[(long)n * K + k] = (f16)lds[tx][ty + p * 8];
    }
  } else {
    int idx = (b - 2 * ntile) * 256 + t;
    if (idx >= 2 * K * 8) return;
    const float* W = (idx < K * 8) ? Wa : Wb;
    const float* A = (idx < K * 8) ? Aa : Ab;
    float* ef = (idx < K * 8) ? efa : efb;
    int t2 = (idx < K * 8) ? idx : idx - K * 8;
    int j = t2 / (K * 4);
    int r = t2 - j * K * 4;
    int h = r / K, f = r - h * K;
    const float* Aj = A + j * Nw;   // A[j], shape [4,dh], Nw = 4*dh
    float s = 0.f;
    for (int d = 0; d < dh; ++d) s += W[f * Nw + h * dh + d] * Aj[h * dh + d];
    ef[j * 4 * K + h * K + f] = s;
  }
}

// ---------- f16 MFMA GEMM, user+item fused: C = A[M,K] @ Bt[N,K]^T ----------
__global__ __launch_bounds__(256) void hgemm2_k(const f16* __restrict__ Aa, const f16* __restrict__ Bta,
                                                f16* __restrict__ Ca, int Ma, int gya,
                                                const f16* __restrict__ Ab, const f16* __restrict__ Btb,
                                                f16* __restrict__ Cb, int Mb,
                                                int N, int K) {
  __shared__ f16 As[128 * 32];
  __shared__ f16 Bs[128 * 32];
  int by = blockIdx.y;
  const f16* A; const f16* Bt; f16* C; int M; int row0;
  if (by < gya) { A = Aa; Bt = Bta; C = Ca; M = Ma; row0 = by * 128; }
  else          { A = Ab; Bt = Btb; C = Cb; M = Mb; row0 = (by - gya) * 128; }
  int tid = threadIdx.x;
  int col0 = blockIdx.x * 128;
  int lane = tid & 63, wv = tid >> 6;
  int wr = (wv & 1) * 64, wc = (wv >> 1) * 64;
  int l16 = lane & 15, q = lane >> 4;
  f32x4 acc[4][4] = {};
  int r = tid >> 2, c8 = (tid & 3) * 8;
  for (int k0 = 0; k0 < K; k0 += 32) {
    int ra = min(row0 + r, M - 1);
    uint4 va = *(const uint4*)&A[(long)ra * K + k0 + c8];
    int ra2 = min(row0 + r + 64, M - 1);
    uint4 va2 = *(const uint4*)&A[(long)ra2 * K + k0 + c8];
    uint4 vb = *(const uint4*)&Bt[(long)(col0 + r) * K + k0 + c8];
    uint4 vb2 = *(const uint4*)&Bt[(long)(col0 + r + 64) * K + k0 + c8];
    *(uint4*)&As[r * 32 + c8] = va;
    *(uint4*)&As[(r + 64) * 32 + c8] = va2;
    *(uint4*)&Bs[r * 32 + c8] = vb;
    *(uint4*)&Bs[(r + 64) * 32 + c8] = vb2;
    __syncthreads();
    f16x8 af[4], bfr[4];
#pragma unroll
    for (int i = 0; i < 4; ++i) {
      af[i] = *(const f16x8*)&As[(wr + i * 16 + l16) * 32 + q * 8];
      bfr[i] = *(const f16x8*)&Bs[(wc + i * 16 + l16) * 32 + q * 8];
    }
#pragma unroll
    for (int i = 0; i < 4; ++i)
#pragma unroll
      for (int j = 0; j < 4; ++j)
        acc[i][j] = __builtin_amdgcn_mfma_f32_16x16x32_f16(af[i], bfr[j], acc[i][j], 0, 0, 0);
    __syncthreads();
  }
#pragma unroll
  for (int i = 0; i < 4; ++i) {
#pragma unroll
    for (int reg = 0; reg < 4; ++reg) {
      int rr = row0 + wr + i * 16 + q * 4 + reg;
      if (rr < M) {
#pragma unroll
        for (int j = 0; j < 4; ++j)
          C[(long)rr * N + col0 + wc + j * 16 + l16] = (f16)acc[i][j][reg];
      }
    }
  }
}

// ---------- layer-0: fused f32->f16 convert + el/er folds; WAVE per node ----------
// Lane holds 2 channels (f32x2 load, f16x2 store). 8 fold partials in-register,
// one 6-step x 8-acc butterfly. No LDS, no barriers (old block-per-node version
// measured 0.53 TB/s = latency-bound on its load->barrier->fold chain).
__global__ __launch_bounds__(256) void eler2_k(
    const float* __restrict__ xu, f16* __restrict__ hbu,
    const float* __restrict__ ef_ui, const float* __restrict__ ef_iu,
    float* __restrict__ el_u, float* __restrict__ er_u,
    const float* __restrict__ xi, f16* __restrict__ hbi,
    float* __restrict__ el_i, float* __restrict__ er_i) {
  const int K = 128;
  int wv = threadIdx.x >> 6, lane = threadIdx.x & 63;
  int g = blockIdx.x * 4 + wv;
  const float* x; f16* hb; const float* elf; const float* erf; float* el; float* er; int n;
  if (g < NUSERS)                { x = xu; hb = hbu; elf = ef_ui; erf = ef_iu + 4 * K; el = el_u; er = er_u; n = g; }
  else if (g < NUSERS + NITEMS)  { x = xi; hb = hbi; elf = ef_iu; erf = ef_ui + 4 * K; el = el_i; er = er_i; n = g - NUSERS; }
  else return;
  long base = (long)n * K;
  int c0 = lane * 2;
  f32x2 xv = *(const f32x2*)&x[base + c0];
  f16x2 hv = { (f16)xv[0], (f16)xv[1] };
  *(f16x2*)&hb[base + c0] = hv;
  float p[8];
#pragma unroll
  for (int jj = 0; jj < 8; ++jj) {
    const float* fr = (jj < 4) ? (elf + jj * K) : (erf + (jj - 4) * K);
    f32x2 f2 = *(const f32x2*)&fr[c0];
    p[jj] = xv[0] * f2[0] + xv[1] * f2[1];
  }
#pragma unroll
  for (int off = 32; off; off >>= 1)
#pragma unroll
    for (int jj = 0; jj < 8; ++jj) p[jj] += __shfl_xor(p[jj], off, 64);
  if (lane == 0) {
    *(float4*)&el[n * 4] = make_float4(p[0], p[1], p[2], p[3]);
    *(float4*)&er[n * 4] = make_float4(p[4], p[5], p[6], p[7]);
  }
}

// ---------- CSR build ----------
__global__ void hist_k(const int* __restrict__ ei, int* __restrict__ degi,
                       const int* __restrict__ eu, int* __restrict__ degu) {
  int e = blockIdx.x * blockDim.x + threadIdx.x;
  if (e < NEDGES) atomicAdd(&degi[ei[e]], 1);
  else if (e < 2 * NEDGES) atomicAdd(&degu[eu[e - NEDGES]], 1);
}

__global__ __launch_bounds__(256) void scan1_k(const int* __restrict__ deg,
                                               int* __restrict__ bsum, int N) {
  __shared__ int red[256];
  int base = blockIdx.x * 1024, t = threadIdx.x;
  int s = 0;
#pragma unroll
  for (int j = 0; j < 4; ++j) { int i = base + t * 4 + j; s += (i < N) ? deg[i] : 0; }
  red[t] = s; __syncthreads();
  for (int off = 128; off; off >>= 1) { if (t < off) red[t] += red[t + off]; __syncthreads(); }
  if (t == 0) bsum[blockIdx.x] = red[0];
}

// exclusive block-sum scan + writes rowptr[N]=NEDGES terminator
__global__ void scan2_k(int* __restrict__ bsum, int nb, int* __restrict__ endp, int endv) {
  if (threadIdx.x == 0) {
    int run = 0;
    for (int i = 0; i < nb; ++i) { int v = bsum[i]; bsum[i] = run; run += v; }
    *endp = endv;
  }
}

__global__ __launch_bounds__(256) void scan3_k(const int* __restrict__ deg,
                                               const int* __restrict__ bsum,
                                               int* __restrict__ rowptr, int N) {
  __shared__ int tsum[256];
  int base = blockIdx.x * 1024, t = threadIdx.x;
  int v[4]; int s = 0;
#pragma unroll
  for (int j = 0; j < 4; ++j) { int i = base + t * 4 + j; v[j] = (i < N) ? deg[i] : 0; s += v[j]; }
  tsum[t] = s; __syncthreads();
  for (int off = 1; off < 256; off <<= 1) {
    int x = (t >= off) ? tsum[t - off] : 0;
    __syncthreads();
    tsum[t] += x;
    __syncthreads();
  }
  int run = bsum[blockIdx.x] + ((t > 0) ? tsum[t - 1] : 0);
#pragma unroll
  for (int j = 0; j < 4; ++j) {
    int i = base + t * 4 + j;
    if (i < N) rowptr[i] = run;
    run += v[j];
  }
}

__global__ void copy2_k(const int* __restrict__ a, int* __restrict__ b, int Na,
                        const int* __restrict__ c, int* __restrict__ d, int Nc) {
  int i = blockIdx.x * blockDim.x + threadIdx.x;
  if (i < Na) b[i] = a[i];
  else if (i < Na + Nc) d[i - Na] = c[i - Na];
}

__global__ void scat_k(const int* __restrict__ ei, const int* __restrict__ eu,
                       int* __restrict__ curi, int* __restrict__ srci,
                       int* __restrict__ curu, int* __restrict__ srcu) {
  int e = blockIdx.x * blockDim.x + threadIdx.x;
  if (e < NEDGES) {
    int p = atomicAdd(&curi[ei[e]], 1);
    srci[p] = eu[e];
  } else if (e < 2 * NEDGES) {
    int e2 = e - NEDGES;
    int p = atomicAdd(&curu[eu[e2]], 1);
    srcu[p] = ei[e2];
  }
}

// ---------- fused segment-softmax + gather; wave per dst ----------
// Output stores NON-TEMPORAL (measured: FETCH -4MB, keeps hs rows in L2).
template <int W, int DH, typename OUT>
__global__ __launch_bounds__(256) void agg_k(
    const float* __restrict__ elA, const float* __restrict__ erA,
    const int* __restrict__ rpA, const int* __restrict__ srcA,
    const f16* __restrict__ hsA, OUT* __restrict__ outA, int nA,
    const float* __restrict__ elB, const float* __restrict__ erB,
    const int* __restrict__ rpB, const int* __restrict__ srcB,
    const f16* __restrict__ hsB, OUT* __restrict__ outB, int nB) {
  constexpr int CPL = W >> 6;                   // channels per lane
  constexpr int SHIFT = (W == 256) ? 9 : 8;     // log2(W * sizeof(f16))
  constexpr bool OF16 = (sizeof(OUT) == 2);
  __shared__ float alds[4][256];   // [wave][slot*4 + head]
  __shared__ int soff[4][64];      // [wave][slot] = src row byte offset
  int wv = threadIdx.x >> 6;
  int g = blockIdx.x * 4 + wv;
  int lane = threadIdx.x & 63;
  const float* el; const float* er; const int* rp; const int* srcv;
  const f16* hs; OUT* outp; int d;
  if (g < nA)           { el = elA; er = erA; rp = rpA; srcv = srcA; hs = hsA; outp = outA; d = g; }
  else if (g < nA + nB) { el = elB; er = erB; rp = rpB; srcv = srcB; hs = hsB; outp = outB; d = g - nA; }
  else return;
  int s0 = rp[d], s1 = rp[d + 1];
  int deg = s1 - s0;
  int c0 = lane * CPL;
  int h = c0 / DH;
  long obase = (long)d * W + c0;
  if (deg == 0) {
#pragma unroll
    for (int q = 0; q < CPL; ++q) outp[obase + q] = (OUT)0.f;
    return;
  }
  const float NEG = -3.0e38f;
  float acc[CPL];
#pragma unroll
  for (int q = 0; q < CPL; ++q) acc[q] = 0.f;
  float inv;

  if (deg <= 64) {
    int hh = lane & 3, p = lane >> 2;
    float er_h = er[d * 4 + hh];
    float vv[4];
    float vmax = NEG;
#pragma unroll
    for (int j = 0; j < 4; ++j) {
      int slot = j * 16 + p;
      vv[j] = NEG;
      if (slot < deg) {
        int sj = srcv[s0 + slot];
        if (hh == 0) soff[wv][slot] = sj << SHIFT;
        float v = el[sj * 4 + hh] + er_h;
        v = v > 0.f ? v : 0.2f * v;
        vv[j] = v;
        vmax = fmaxf(vmax, v);
      }
    }
#pragma unroll
    for (int off = 4; off < 64; off <<= 1) vmax = fmaxf(vmax, __shfl_xor(vmax, off, 64));
    float ssum = 0.f;
#pragma unroll
    for (int j = 0; j < 4; ++j) {
      int slot = j * 16 + p;
      if (slot < deg) {
        float e = expf(vv[j] - vmax);
        alds[wv][slot * 4 + hh] = e;
        ssum += e;
      } else {
        alds[wv][slot * 4 + hh] = 0.f;       // zero-pad alpha
        if (hh == 0) soff[wv][slot] = 0;     // pad offset -> row 0 (always cached)
      }
    }
#pragma unroll
    for (int off = 4; off < 64; off <<= 1) ssum += __shfl_xor(ssum, off, 64);
    float Sh = __shfl(ssum, (lane & ~3) | h, 64);
    inv = 1.0f / Sh;
    const char* hbase = (const char*)hs + (size_t)c0 * sizeof(f16);
    int degp = (deg + 3) & ~3;
    for (int j = 0; j < degp; j += 4) {
      float aj[4]; int oj[4];
#pragma unroll
      for (int u = 0; u < 4; ++u) {
        aj[u] = alds[wv][(j + u) * 4 + h];
        oj[u] = soff[wv][j + u];
      }
      if constexpr (CPL == 4) {
        f16x4 vj[4];
#pragma unroll
        for (int u = 0; u < 4; ++u)
          vj[u] = *(const f16x4*)(hbase + (size_t)(unsigned)oj[u]);
#pragma unroll
        for (int u = 0; u < 4; ++u) {
          acc[0] += aj[u] * (float)vj[u][0];
          acc[1] += aj[u] * (float)vj[u][1];
          acc[2] += aj[u] * (float)vj[u][2];
          acc[3] += aj[u] * (float)vj[u][3];
        }
      } else {
        f16x2 vj[4];
#pragma unroll
        for (int u = 0; u < 4; ++u)
          vj[u] = *(const f16x2*)(hbase + (size_t)(unsigned)oj[u]);
#pragma unroll
        for (int u = 0; u < 4; ++u) {
          acc[0] += aj[u] * (float)vj[u][0];
          acc[1] += aj[u] * (float)vj[u][1];
        }
      }
    }
  } else {
    // ---- generic fallback (deg > 64): strided two-pass + serial gather ----
    float4 er4 = *(const float4*)&er[d * 4];
    float m0 = NEG, m1 = NEG, m2 = NEG, m3 = NEG;
    for (int k = s0 + lane; k < s1; k += 64) {
      int s = srcv[k];
      float4 e4 = *(const float4*)&el[s * 4];
      float v;
      v = e4.x + er4.x; v = v > 0.f ? v : 0.2f * v; m0 = fmaxf(m0, v);
      v = e4.y + er4.y; v = v > 0.f ? v : 0.2f * v; m1 = fmaxf(m1, v);
      v = e4.z + er4.z; v = v > 0.f ? v : 0.2f * v; m2 = fmaxf(m2, v);
      v = e4.w + er4.w; v = v > 0.f ? v : 0.2f * v; m3 = fmaxf(m3, v);
    }
#pragma unroll
    for (int off = 32; off; off >>= 1) {
      m0 = fmaxf(m0, __shfl_xor(m0, off, 64));
      m1 = fmaxf(m1, __shfl_xor(m1, off, 64));
      m2 = fmaxf(m2, __shfl_xor(m2, off, 64));
      m3 = fmaxf(m3, __shfl_xor(m3, off, 64));
    }
    float S0 = 0.f, S1 = 0.f, S2 = 0.f, S3 = 0.f;
    for (int k = s0 + lane; k < s1; k += 64) {
      int s = srcv[k];
      float4 e4 = *(const float4*)&el[s * 4];
      float v;
      v = e4.x + er4.x; v = v > 0.f ? v : 0.2f * v; S0 += expf(v - m0);
      v = e4.y + er4.y; v = v > 0.f ? v : 0.2f * v; S1 += expf(v - m1);
      v = e4.z + er4.z; v = v > 0.f ? v : 0.2f * v; S2 += expf(v - m2);
      v = e4.w + er4.w; v = v > 0.f ? v : 0.2f * v; S3 += expf(v - m3);
    }
#pragma unroll
    for (int off = 32; off; off >>= 1) {
      S0 += __shfl_xor(S0, off, 64);
      S1 += __shfl_xor(S1, off, 64);
      S2 += __shfl_xor(S2, off, 64);
      S3 += __shfl_xor(S3, off, 64);
    }
    float mh = h == 0 ? m0 : h == 1 ? m1 : h == 2 ? m2 : m3;
    float Sh = h == 0 ? S0 : h == 1 ? S1 : h == 2 ? S2 : S3;
    float erh = h == 0 ? er4.x : h == 1 ? er4.y : h == 2 ? er4.z : er4.w;
    inv = 1.0f / Sh;
    for (int k = s0; k < s1; ++k) {
      int s = srcv[k];
      float v = el[s * 4 + h] + erh; v = v > 0.f ? v : 0.2f * v;
      float a = expf(v - mh);
      const f16* row = &hs[(long)s * W + c0];
      if constexpr (CPL == 4) {
        f16x4 hv = *(const f16x4*)row;
        acc[0] += a * (float)hv[0]; acc[1] += a * (float)hv[1];
        acc[2] += a * (float)hv[2]; acc[3] += a * (float)hv[3];
      } else {
        f16x2 hv = *(const f16x2*)row;
        acc[0] += a * (float)hv[0]; acc[1] += a * (float)hv[1];
      }
    }
  }
  if constexpr (OF16) {
    if constexpr (CPL == 4) {
      f16x4 o = { (f16)(acc[0] * inv), (f16)(acc[1] * inv), (f16)(acc[2] * inv), (f16)(acc[3] * inv) };
      __builtin_nontemporal_store(o, (f16x4*)&outp[obase]);
    } else {
      f16x2 o = { (f16)(acc[0] * inv), (f16)(acc[1] * inv) };
      __builtin_nontemporal_store(o, (f16x2*)&outp[obase]);
    }
  } else {
    if constexpr (CPL == 4) {
      f32x4 o = { acc[0] * inv, acc[1] * inv, acc[2] * inv, acc[3] * inv };
      __builtin_nontemporal_store(o, (f32x4*)&outp[obase]);
    } else {
      f32x2 o = { acc[0] * inv, acc[1] * inv };
      __builtin_nontemporal_store(o, (f32x2*)&outp[obase]);
    }
  }
}

// ---------- BN stats (f16 input), both sides; per-layer sum regions ----------
__global__ __launch_bounds__(256) void bn_stats2_k(const f16* __restrict__ xu, float* __restrict__ su, int Nu, int gU,
                                                   const f16* __restrict__ xi, float* __restrict__ si, int Ni) {
  const int C = 256;
  int b = blockIdx.x;
  const f16* x; float* sums; int N; int r0;
  if (b < gU) { x = xu; sums = su; N = Nu; r0 = b * 64; }
  else        { x = xi; sums = si; N = Ni; r0 = (b - gU) * 64; }
  int c = threadIdx.x;
  int r1 = min(r0 + 64, N);
  float s = 0.f, s2 = 0.f;
  for (int r = r0; r < r1; ++r) {
    float v = (float)x[(long)r * C + c];
    s += v; s2 += v * v;
  }
  atomicAdd(&sums[c], s);
  atomicAdd(&sums[C + c], s2);
}

// ---------- fused BN apply + activation -> f16 AND next-layer el/er; WAVE per node ----------
// Lane holds 4 channels (f16x4). BN tables (sums/gamma/beta: 2KB) via float4,
// L1-hot. 8 fold partials in-register + one 6-step x 8-acc butterfly.
// No LDS, no barriers (old block-per-node version was latency-bound).
__global__ __launch_bounds__(256) void bn_fused_k(
    const f16* __restrict__ xu, const float* __restrict__ su, const float* __restrict__ gbu,
    f16* __restrict__ yu, int Nu,
    const f16* __restrict__ xi, const float* __restrict__ si, const float* __restrict__ gbi,
    f16* __restrict__ yi, int Ni,
    const float* __restrict__ efu, const float* __restrict__ efiu,   // next-layer folds, K=256
    float* __restrict__ el_u, float* __restrict__ er_u,
    float* __restrict__ el_i, float* __restrict__ er_i, int act) {
  const int Kn = 256;
  int wv = threadIdx.x >> 6, lane = threadIdx.x & 63;
  int g = blockIdx.x * 4 + wv;
  const f16* x; const float* sums; const float* gb; f16* y; int n; int N;
  const float* elf; const float* erf; float* el; float* er;
  if (g < Nu)           { x = xu; sums = su; gb = gbu; y = yu; n = g; N = Nu; elf = efu;  erf = efiu + 4 * Kn; el = el_u; er = er_u; }
  else if (g < Nu + Ni) { x = xi; sums = si; gb = gbi; y = yi; n = g - Nu; N = Ni; elf = efiu; erf = efu + 4 * Kn;  el = el_i; er = er_i; }
  else return;
  long base = (long)n * 256;
  int c0 = lane * 4;
  f16x4 xv = *(const f16x4*)&x[base + c0];
  float4 sm = *(const float4*)&sums[c0];
  float4 q2 = *(const float4*)&sums[256 + c0];
  float4 gg = *(const float4*)&gb[c0];
  float4 bb = *(const float4*)&gb[256 + c0];
  float ms[4] = { sm.x, sm.y, sm.z, sm.w };
  float qs[4] = { q2.x, q2.y, q2.z, q2.w };
  float gs[4] = { gg.x, gg.y, gg.z, gg.w };
  float bs[4] = { bb.x, bb.y, bb.z, bb.w };
  float inv_n = 1.0f / (float)N;
  float v[4];
  f16x4 ov;
#pragma unroll
  for (int q = 0; q < 4; ++q) {
    float mean = ms[q] * inv_n;
    float var = qs[q] * inv_n - mean * mean;
    float t = gs[q] * ((float)xv[q] - mean) * rsqrtf(var + 1e-5f) + bs[q];
    t = act ? tanhf(t) : (t > 0.f ? t : 0.01f * t);
    v[q] = t;
    ov[q] = (f16)t;
  }
  *(f16x4*)&y[base + c0] = ov;
  float p[8];
#pragma unroll
  for (int jj = 0; jj < 8; ++jj) {
    const float* fr = (jj < 4) ? (elf + jj * Kn) : (erf + (jj - 4) * Kn);
    float4 f4 = *(const float4*)&fr[c0];
    p[jj] = v[0] * f4.x + v[1] * f4.y + v[2] * f4.z + v[3] * f4.w;
  }
#pragma unroll
  for (int off = 32; off; off >>= 1)
#pragma unroll
    for (int jj = 0; jj < 8; ++jj) p[jj] += __shfl_xor(p[jj], off, 64);
  if (lane == 0) {
    *(float4*)&el[n * 4] = make_float4(p[0], p[1], p[2], p[3]);
    *(float4*)&er[n * 4] = make_float4(p[4], p[5], p[6], p[7]);
  }
}

extern "C" void kernel_launch(void* const* d_in, const int* in_sizes, int n_in,
                              void* d_out, int out_size, void* d_ws, size_t ws_size,
                              hipStream_t stream) {
  const float* x_user = (const float*)d_in[0];
  const float* x_item = (const float*)d_in[1];
  const int* eu = (const int*)d_in[2];
  const int* ei = (const int*)d_in[3];
  const float *Wm[4][2], *Am[4][2];
  for (int L = 0; L < 4; ++L) {
    Wm[L][0] = (const float*)d_in[4 + L * 4 + 0];
    Am[L][0] = (const float*)d_in[4 + L * 4 + 1];
    Wm[L][1] = (const float*)d_in[4 + L * 4 + 2];
    Am[L][1] = (const float*)d_in[4 + L * 4 + 3];
  }
  const float* bnu = (const float*)d_in[20];
  const float* bni = (const float*)d_in[21];
  float* out = (float*)d_out;

  float* ws = (float*)d_ws;
  size_t o = 0;
  float* el_u = ws + o; o += (size_t)NUSERS * 4;
  float* er_u = ws + o; o += (size_t)NUSERS * 4;
  float* el_i = ws + o; o += (size_t)NITEMS * 4;
  float* er_i = ws + o; o += (size_t)NITEMS * 4;
  float* ef_all[4][2];
  for (int L = 0; L < 4; ++L)
    for (int rl = 0; rl < 2; ++rl) { ef_all[L][rl] = ws + o; o += 2048; }
  // f16 buffers (offsets in float units; all 16B aligned)
  f16* hb_u   = (f16*)(ws + o); o += (size_t)NUSERS * 128;
  f16* hb_i   = (f16*)(ws + o); o += (size_t)NITEMS * 128;
  f16* hsb_u  = (f16*)(ws + o); o += (size_t)NUSERS * 128;
  f16* hsb_i  = (f16*)(ws + o); o += (size_t)NITEMS * 128;
  f16* aggh_u = (f16*)(ws + o); o += (size_t)NUSERS * 128;
  f16* aggh_i = (f16*)(ws + o); o += (size_t)NITEMS * 128;
  f16* Bt_all[4][2];
  for (int L = 0; L < 4; ++L) {
    int K = (L == 0) ? 128 : 256;
    int W = (L == 3) ? 128 : 256;
    for (int rl = 0; rl < 2; ++rl) { Bt_all[L][rl] = (f16*)(ws + o); o += (size_t)K * W / 2; }
  }
  // BN sums (3 layers x (512u + 512i)) + CSR deg: contiguous => single memset
  float* bns_all = ws + o; o += 3 * 1024;
  int* deg_i    = (int*)(ws + o); o += NITEMS;
  int* deg_u    = (int*)(ws + o); o += NUSERS;
  int* rowptr_i = (int*)(ws + o); o += NITEMS + 4;
  int* rowptr_u = (int*)(ws + o); o += NUSERS + 4;
  int* cur_i    = (int*)(ws + o); o += NITEMS;
  int* cur_u    = (int*)(ws + o); o += NUSERS;
  int* bsum     = (int*)(ws + o); o += 256;
  int* csrsrc_i = (int*)(ws + o); o += NEDGES + 4;
  int* csrsrc_u = (int*)(ws + o); o += NEDGES + 4;

  const int gE2 = (2 * NEDGES + 255) / 256;
  const int nb_i = (NITEMS + 1023) / 1024;
  const int nb_u = (NUSERS + 1023) / 1024;
  const int gU = (NUSERS + 63) / 64;
  const int gI = (NITEMS + 63) / 64;
  const int gNode = (NUSERS + NITEMS + 3) / 4;

  // ---- zero BN sums + deg in one memset; CSR build (once) ----
  hipMemsetAsync(bns_all, 0, (3 * 1024 + NITEMS + NUSERS) * sizeof(float), stream);
  hist_k<<<dim3(gE2), dim3(256), 0, stream>>>(ei, deg_i, eu, deg_u);
  scan1_k<<<dim3(nb_i), dim3(256), 0, stream>>>(deg_i, bsum, NITEMS);
  scan2_k<<<dim3(1), dim3(64), 0, stream>>>(bsum, nb_i, rowptr_i + NITEMS, NEDGES);
  scan3_k<<<dim3(nb_i), dim3(256), 0, stream>>>(deg_i, bsum, rowptr_i, NITEMS);
  scan1_k<<<dim3(nb_u), dim3(256), 0, stream>>>(deg_u, bsum, NUSERS);
  scan2_k<<<dim3(1), dim3(64), 0, stream>>>(bsum, nb_u, rowptr_u + NUSERS, NEDGES);
  scan3_k<<<dim3(nb_u), dim3(256), 0, stream>>>(deg_u, bsum, rowptr_u, NUSERS);
  copy2_k<<<dim3((NITEMS + NUSERS + 255) / 256), dim3(256), 0, stream>>>(rowptr_i, cur_i, NITEMS, rowptr_u, cur_u, NUSERS);
  scat_k<<<dim3(gE2), dim3(256), 0, stream>>>(ei, eu, cur_i, csrsrc_i, cur_u, csrsrc_u);

  // ---- all layer preps upfront (tiled Bt transpose + el/er folds) ----
  for (int L = 0; L < 4; ++L) {
    int K = (L == 0) ? 128 : 256;
    int dh = (L == 3) ? 32 : 64;
    int W = 4 * dh;
    int ntile2 = 2 * (K / 32) * (W / 32);
    int gef = (2 * K * 8 + 255) / 256;
    prep2_k<<<dim3(ntile2 + gef), dim3(256), 0, stream>>>(
        Wm[L][0], Am[L][0], Bt_all[L][0], ef_all[L][0],
        Wm[L][1], Am[L][1], Bt_all[L][1], ef_all[L][1], K, W, dh);
  }

  // layer-0: fused f32->f16 convert + el/er (wave per node)
  eler2_k<<<dim3(gNode), dim3(256), 0, stream>>>(
      x_user, hb_u, ef_all[0][0], ef_all[0][1], el_u, er_u,
      x_item, hb_i, el_i, er_i);

  int K = 128;
  const int gAgg = gNode;
  const int gya = (NUSERS + 127) / 128, gyb = (NITEMS + 127) / 128;
  for (int L = 0; L < 4; ++L) {
    const int dh = (L == 3) ? 32 : 64;
    const int W = 4 * dh;

    hgemm2_k<<<dim3(W / 128, gya + gyb), dim3(256), 0, stream>>>(
        hb_u, Bt_all[L][0], hsb_u, NUSERS, gya, hb_i, Bt_all[L][1], hsb_i, NITEMS, W, K);

    if (L < 3) {
      float* su = bns_all + (size_t)L * 1024;
      float* si = su + 512;
      agg_k<256, 64, f16><<<dim3(gAgg), dim3(256), 0, stream>>>(
          el_u, er_i, rowptr_i, csrsrc_i, hsb_u, aggh_i, NITEMS,
          el_i, er_u, rowptr_u, csrsrc_u, hsb_i, aggh_u, NUSERS);
      bn_stats2_k<<<dim3(gU + gI), dim3(256), 0, stream>>>(aggh_u, su, NUSERS, gU, aggh_i, si, NITEMS);
      bn_fused_k<<<dim3(gNode), dim3(256), 0, stream>>>(
          aggh_u, su, bnu + L * 512, hb_u, NUSERS,
          aggh_i, si, bni + L * 512, hb_i, NITEMS,
          ef_all[L + 1][0], ef_all[L + 1][1],
          el_u, er_u, el_i, er_i, L == 2);
      K = 256;
    } else {
      agg_k<128, 32, float><<<dim3(gAgg), dim3(256), 0, stream>>>(
          el_u, er_i, rowptr_i, csrsrc_i, hsb_u, out + (size_t)NUSERS * 128, NITEMS,
          el_i, er_u, rowptr_u, csrsrc_u, hsb_i, out, NUSERS);
    }
  }
}